// Round 1
// baseline (2026.933 us; speedup 1.0000x reference)
//
#include <hip/hip_runtime.h>
#include <hip/hip_bf16.h>

#define T_LEN 1024
#define CDIM  768
#define HNUM  12
#define KDIM  64
#define LNUM  6
#define FDIM  2688
#define VDIM  50304
#define NCH   16     // wkv chunks
#define LCH   64     // chunk length

typedef __attribute__((ext_vector_type(4))) float f32x4;
typedef __attribute__((ext_vector_type(8))) short s16x8;

__device__ __forceinline__ ushort f2bf(float f) {
    union { float fv; unsigned u; } v; v.fv = f;
    unsigned r = v.u + 0x7fffu + ((v.u >> 16) & 1u);   // RNE
    return (ushort)(r >> 16);
}

// ---------------- LayerNorm over C=768 (block=256, 3 elems/thread) ----------
template <typename OT>
__global__ __launch_bounds__(256)
void k_ln(const float* __restrict__ x, const float* __restrict__ wb,
          OT* __restrict__ out) {
    int t = blockIdx.x, tid = threadIdx.x;
    float v[3]; float s = 0.f, s2 = 0.f;
    #pragma unroll
    for (int j = 0; j < 3; j++) {
        v[j] = x[(size_t)t * CDIM + tid + j * 256];
        s += v[j]; s2 += v[j] * v[j];
    }
    #pragma unroll
    for (int m = 32; m; m >>= 1) { s += __shfl_xor(s, m); s2 += __shfl_xor(s2, m); }
    __shared__ float rs[4], rq[4];
    int w = tid >> 6;
    if ((tid & 63) == 0) { rs[w] = s; rq[w] = s2; }
    __syncthreads();
    s = rs[0] + rs[1] + rs[2] + rs[3];
    s2 = rq[0] + rq[1] + rq[2] + rq[3];
    float mu = s * (1.f / CDIM);
    float var = s2 * (1.f / CDIM) - mu * mu;
    float inv = rsqrtf(var + 1e-5f);
    #pragma unroll
    for (int j = 0; j < 3; j++) {
        int c = tid + j * 256;
        float o = (v[j] - mu) * inv * wb[c] + wb[CDIM + c];
        if constexpr (__is_same(OT, ushort)) out[(size_t)t * CDIM + c] = f2bf(o);
        else out[(size_t)t * CDIM + c] = o;
    }
}

// ---------------- embed lookup + LN ----------------
__global__ __launch_bounds__(256)
void k_embed_ln(const int* __restrict__ tok, const float* __restrict__ embed,
                const float* __restrict__ wb, float* __restrict__ xout) {
    int t = blockIdx.x, tid = threadIdx.x;
    const float* row = embed + (size_t)tok[t] * CDIM;
    float v[3]; float s = 0.f, s2 = 0.f;
    #pragma unroll
    for (int j = 0; j < 3; j++) {
        v[j] = row[tid + j * 256]; s += v[j]; s2 += v[j] * v[j];
    }
    #pragma unroll
    for (int m = 32; m; m >>= 1) { s += __shfl_xor(s, m); s2 += __shfl_xor(s2, m); }
    __shared__ float rs[4], rq[4];
    int w = tid >> 6;
    if ((tid & 63) == 0) { rs[w] = s; rq[w] = s2; }
    __syncthreads();
    s = rs[0] + rs[1] + rs[2] + rs[3];
    s2 = rq[0] + rq[1] + rq[2] + rq[3];
    float mu = s * (1.f / CDIM);
    float var = s2 * (1.f / CDIM) - mu * mu;
    float inv = rsqrtf(var + 1e-5f);
    #pragma unroll
    for (int j = 0; j < 3; j++) {
        int c = tid + j * 256;
        xout[(size_t)t * CDIM + c] = (v[j] - mu) * inv * wb[c] + wb[CDIM + c];
    }
}

// ---------------- token-shift lerp -> NM bf16 mix buffers ----------------
template <int NM>
__global__ __launch_bounds__(256)
void k_lerp(const float* __restrict__ xn, const float* __restrict__ ts,
            ushort* __restrict__ mix) {
    int t = blockIdx.x, tid = threadIdx.x;
    #pragma unroll
    for (int j = 0; j < 3; j++) {
        int c = tid + j * 256;
        float b = xn[(size_t)t * CDIM + c];
        float a = (t > 0) ? xn[(size_t)(t - 1) * CDIM + c] : 0.f;
        #pragma unroll
        for (int m = 0; m < NM; m++) {
            float wv = ts[m * CDIM + c];
            mix[((size_t)m * T_LEN + t) * CDIM + c] = f2bf(a + (b - a) * wv);
        }
    }
}

// ---------------- bf16 MFMA GEMM: C = A(bf16 MxK) @ B(f32 KxN, converted) ----
// EPI: 0 = plain f32, 1 = resid+f32, 2 = relu^2 -> bf16, 3 = resid + v*sigmoid(gate)
template <int BM, int BN, int EPI>
__global__ __launch_bounds__(256)
void k_gemm(const ushort* __restrict__ A, const float* __restrict__ Bw,
            float* __restrict__ Cf, ushort* __restrict__ Cb,
            const float* __restrict__ resid, const float* __restrict__ gate,
            int N, int K) {
    constexpr int LDP = 40;                 // padded ushort row stride (80B)
    __shared__ __align__(16) ushort Al[BM * LDP];
    __shared__ __align__(16) ushort Bl[BN * LDP];
    const int tid = threadIdx.x, lane = tid & 63, wave = tid >> 6;
    const int nb = blockIdx.x * BN, mb = blockIdx.y * BM;
    constexpr int WM = BM / 2, WN = BN / 2, FM = WM / 16, FN = WN / 16;
    const int wm = (wave >> 1) * WM, wn = (wave & 1) * WN;
    constexpr int A_ITERS = (BM * 32) / (256 * 8);
    constexpr int B_ITERS = (32 * BN) / (256 * 4);

    f32x4 acc[FM][FN];
    #pragma unroll
    for (int i = 0; i < FM; i++)
        #pragma unroll
        for (int j = 0; j < FN; j++) acc[i][j] = (f32x4)0.f;

    for (int k0 = 0; k0 < K; k0 += 32) {
        // stage A tile [BM][32] bf16 (already bf16 in global)
        #pragma unroll
        for (int it = 0; it < A_ITERS; ++it) {
            int idx = tid * 8 + it * 2048;
            int row = idx >> 5, kk = idx & 31;
            const ushort* src = A + (size_t)(mb + row) * K + k0 + kk;
            *(uint4*)&Al[row * LDP + kk] = *(const uint4*)src;
        }
        // stage B tile [32][BN] f32 -> transposed bf16 LDS [n][k], k-group XOR swizzle
        #pragma unroll
        for (int it = 0; it < B_ITERS; ++it) {
            int idx = tid * 4 + it * 1024;
            int k = idx / BN, n = idx & (BN - 1);
            const float* src = Bw + (size_t)(k0 + k) * N + nb + n;
            float4 f = *(const float4*)src;
            const float* fp = (const float*)&f;
            #pragma unroll
            for (int e = 0; e < 4; e++) {
                int nn = n + e;
                int kg = (k >> 3) ^ ((nn >> 4) & 3);
                Bl[nn * LDP + kg * 8 + (k & 7)] = f2bf(fp[e]);
            }
        }
        __syncthreads();
        s16x8 af[FM], bfr[FN];
        const int kq = lane >> 4, ln15 = lane & 15;
        #pragma unroll
        for (int i = 0; i < FM; i++) {
            int row = wm + i * 16 + ln15;
            af[i] = *(const s16x8*)&Al[row * LDP + kq * 8];
        }
        #pragma unroll
        for (int j = 0; j < FN; j++) {
            int col = wn + j * 16 + ln15;
            int kg = kq ^ ((col >> 4) & 3);
            bfr[j] = *(const s16x8*)&Bl[col * LDP + kg * 8];
        }
        #pragma unroll
        for (int i = 0; i < FM; i++)
            #pragma unroll
            for (int j = 0; j < FN; j++)
                acc[i][j] = __builtin_amdgcn_mfma_f32_16x16x32_bf16(
                    af[i], bfr[j], acc[i][j], 0, 0, 0);
        __syncthreads();
    }
    // epilogue: D row = (lane>>4)*4 + r, col = lane&15  [verified layout]
    #pragma unroll
    for (int i = 0; i < FM; i++) {
        int rbase = mb + wm + i * 16 + (lane >> 4) * 4;
        #pragma unroll
        for (int j = 0; j < FN; j++) {
            int col = nb + wn + j * 16 + (lane & 15);
            #pragma unroll
            for (int r = 0; r < 4; r++) {
                size_t idx = (size_t)(rbase + r) * N + col;
                float vv = acc[i][j][r];
                if constexpr (EPI == 0) {
                    Cf[idx] = vv;
                } else if constexpr (EPI == 1) {
                    Cf[idx] = resid[idx] + vv;
                } else if constexpr (EPI == 2) {
                    float z = vv > 0.f ? vv * vv : 0.f;
                    Cb[idx] = f2bf(z);
                } else {
                    float gv = gate[idx];
                    Cf[idx] = resid[idx] + vv / (1.f + __expf(-gv));
                }
            }
        }
    }
}

// ---------------- WKV chunked scan ----------------
// pass1: per-chunk local state  Stil[c][h][k][v] = sum_j w^(63-j) k_j[k] v_j[v]
__global__ __launch_bounds__(256)
void k_wkv1(const float* __restrict__ kb, const float* __restrict__ vb,
            const float* __restrict__ decay, float* __restrict__ Stil) {
    int c = blockIdx.x / HNUM, h = blockIdx.x % HNUM;
    __shared__ float kl[4096], vl[4096], wsh[64];
    int tid = threadIdx.x;
    for (int idx = tid; idx < 4096; idx += 256) {
        int j = idx >> 6, cc = idx & 63;
        size_t g = (size_t)(c * LCH + j) * CDIM + h * 64 + cc;
        kl[idx] = kb[g]; vl[idx] = vb[g];
    }
    if (tid < 64) wsh[tid] = expf(-expf(decay[h * 64 + tid]));
    __syncthreads();
    int k = tid >> 2, v0 = (tid & 3) * 16;
    float w = wsh[k], f = 1.f;
    float s[16];
    #pragma unroll
    for (int i = 0; i < 16; i++) s[i] = 0.f;
    for (int j = 63; j >= 0; --j) {
        float kw = kl[j * 64 + k] * f;
        #pragma unroll
        for (int i = 0; i < 16; i++) s[i] += kw * vl[j * 64 + v0 + i];
        f *= w;
    }
    float* dst = Stil + ((size_t)(c * HNUM + h) << 12) + k * 64 + v0;
    #pragma unroll
    for (int i = 0; i < 16; i++) dst[i] = s[i];
}

// pass2: chunk-boundary stitch: S0[c] = state before chunk c
__global__ __launch_bounds__(256)
void k_wkv2(const float* __restrict__ Stil, const float* __restrict__ decay,
            float* __restrict__ S0) {
    int h = blockIdx.x, tid = threadIdx.x;
    int k = tid >> 2, v0 = (tid & 3) * 16;
    float wLc = expf(-64.f * expf(decay[h * 64 + k]));   // w^64
    float s[16];
    #pragma unroll
    for (int i = 0; i < 16; i++) s[i] = 0.f;
    for (int c = 0; c < NCH; c++) {
        size_t base = ((size_t)(c * HNUM + h) << 12) + k * 64 + v0;
        float* dst = S0 + base;
        const float* src = Stil + base;
        #pragma unroll
        for (int i = 0; i < 16; i++) { dst[i] = s[i]; s[i] = s[i] * wLc + src[i]; }
    }
}

// pass3: replay chunk with true start state; out_t = r.(S + k*v*bonus); S = wS + k*v
__global__ __launch_bounds__(256)
void k_wkv3(const float* __restrict__ rb, const float* __restrict__ kb,
            const float* __restrict__ vb, const float* __restrict__ S0,
            const float* __restrict__ decay, const float* __restrict__ bonus,
            float* __restrict__ outb) {
    int c = blockIdx.x / HNUM, h = blockIdx.x % HNUM;
    __shared__ float rl[4096], kl[4096], vl[4096], wsh[64], bsh[64];
    __shared__ float part[4][64];
    int tid = threadIdx.x;
    for (int idx = tid; idx < 4096; idx += 256) {
        int j = idx >> 6, cc = idx & 63;
        size_t g = (size_t)(c * LCH + j) * CDIM + h * 64 + cc;
        rl[idx] = rb[g]; kl[idx] = kb[g]; vl[idx] = vb[g];
    }
    if (tid < 64) {
        wsh[tid] = expf(-expf(decay[h * 64 + tid]));
        bsh[tid] = bonus[h * 64 + tid];
    }
    int v = tid & 63, kg = tid >> 6;
    float S[16];
    const float* s0p = S0 + ((size_t)(c * HNUM + h) << 12);
    #pragma unroll
    for (int i = 0; i < 16; i++) S[i] = s0p[(kg * 16 + i) * 64 + v];
    __syncthreads();
    for (int j = 0; j < 64; j++) {
        float vj = vl[j * 64 + v];
        float rsum = 0.f;
        #pragma unroll
        for (int i = 0; i < 16; i++) {
            int kk = kg * 16 + i;
            float a = kl[j * 64 + kk] * vj;           // broadcast LDS reads
            rsum += rl[j * 64 + kk] * (S[i] + a * bsh[kk]);
            S[i] = S[i] * wsh[kk] + a;
        }
        part[kg][v] = rsum;
        __syncthreads();
        if (kg == 0)
            outb[(size_t)(c * LCH + j) * CDIM + h * 64 + v] =
                part[0][v] + part[1][v] + part[2][v] + part[3][v];
        __syncthreads();
    }
}

// ---------------- GroupNorm (per head of 64) * silu(g) -> bf16 ----------------
__global__ __launch_bounds__(768)
void k_gn_gate(const float* __restrict__ xin, const float* __restrict__ g,
               const float* __restrict__ wb, ushort* __restrict__ y) {
    int t = blockIdx.x, c = threadIdx.x;          // 768 threads = 12 waves = 12 heads
    float x = xin[(size_t)t * CDIM + c];
    float s = x, s2 = x * x;
    #pragma unroll
    for (int m = 32; m; m >>= 1) { s += __shfl_xor(s, m); s2 += __shfl_xor(s2, m); }
    float mu = s * (1.f / 64.f);
    float var = s2 * (1.f / 64.f) - mu * mu;
    float xg = (x - mu) * rsqrtf(var + 6.4e-4f);
    float gv = g[(size_t)t * CDIM + c];
    float silu = gv / (1.f + __expf(-gv));
    y[(size_t)t * CDIM + c] = f2bf((xg * wb[c] + wb[CDIM + c]) * silu);
}

// ---------------- host ----------------
extern "C" void kernel_launch(void* const* d_in, const int* in_sizes, int n_in,
                              void* d_out, int out_size, void* d_ws, size_t ws_size,
                              hipStream_t stream) {
    const int*   tok      = (const int*)d_in[0];
    const float* embed    = (const float*)d_in[1];
    const float* embed_ln = (const float*)d_in[2];
    const float* tm_ln    = (const float*)d_in[3];
    const float* tm_ts    = (const float*)d_in[4];
    const float* tm_Wr    = (const float*)d_in[5];
    const float* tm_Wk    = (const float*)d_in[6];
    const float* tm_Wv    = (const float*)d_in[7];
    const float* tm_Wg    = (const float*)d_in[8];
    const float* tm_Wo    = (const float*)d_in[9];
    const float* tm_bonus = (const float*)d_in[10];
    const float* tm_decay = (const float*)d_in[11];
    const float* tm_gn    = (const float*)d_in[12];
    const float* cm_ln    = (const float*)d_in[13];
    const float* cm_ts    = (const float*)d_in[14];
    const float* cm_Win   = (const float*)d_in[15];
    const float* cm_Wout  = (const float*)d_in[16];
    const float* cm_Wg    = (const float*)d_in[17];
    const float* head_ln  = (const float*)d_in[18];
    const float* unembed  = (const float*)d_in[19];
    float* out = (float*)d_out;

    const size_t TC = (size_t)T_LEN * CDIM;
    char* wp = (char*)d_ws;
    auto alloc = [&](size_t bytes) {
        char* p = wp; wp += (bytes + 255) & ~(size_t)255; return p;
    };
    float*  x    = (float*)alloc(TC * 4);
    float*  xn   = (float*)alloc(TC * 4);
    ushort* mix  = (ushort*)alloc(4 * TC * 2);
    float*  rb   = (float*)alloc(TC * 4);
    float*  kb   = (float*)alloc(TC * 4);
    float*  vb   = (float*)alloc(TC * 4);
    float*  gb   = (float*)alloc(TC * 4);
    float*  wkvo = (float*)alloc(TC * 4);
    ushort* y    = (ushort*)alloc(TC * 2);
    ushort* hb   = (ushort*)alloc((size_t)T_LEN * FDIM * 2);
    float*  Stil = (float*)alloc((size_t)NCH * HNUM * 4096 * 4);
    float*  S0   = (float*)alloc((size_t)NCH * HNUM * 4096 * 4);
    if ((size_t)(wp - (char*)d_ws) > ws_size) return;   // fail loudly, no UB

    dim3 g64(CDIM / 64, T_LEN / 64);       // (12,16)
    dim3 gWin(FDIM / 128, T_LEN / 128);    // (21,8)
    dim3 gHead(VDIM / 128, T_LEN / 128);   // (393,8)

    k_embed_ln<<<T_LEN, 256, 0, stream>>>(tok, embed, embed_ln, x);

    for (int l = 0; l < LNUM; l++) {
        const float* Wr  = tm_Wr  + (size_t)l * CDIM * CDIM;
        const float* Wk  = tm_Wk  + (size_t)l * CDIM * CDIM;
        const float* Wv  = tm_Wv  + (size_t)l * CDIM * CDIM;
        const float* Wg  = tm_Wg  + (size_t)l * CDIM * CDIM;
        const float* Wo  = tm_Wo  + (size_t)l * CDIM * CDIM;
        const float* Win = cm_Win + (size_t)l * CDIM * FDIM;
        const float* Wou = cm_Wout+ (size_t)l * FDIM * CDIM;
        const float* Wcg = cm_Wg  + (size_t)l * CDIM * CDIM;
        const float* dec = tm_decay + (size_t)l * HNUM * KDIM;
        const float* bon = tm_bonus + (size_t)l * HNUM * KDIM;

        // ---- time mixer ----
        k_ln<float><<<T_LEN, 256, 0, stream>>>(x, tm_ln + (size_t)l * 2 * CDIM, xn);
        k_lerp<4><<<T_LEN, 256, 0, stream>>>(xn, tm_ts + (size_t)l * 4 * CDIM, mix);
        k_gemm<64,64,0><<<g64,256,0,stream>>>(mix,        Wr, rb, nullptr, nullptr, nullptr, CDIM, CDIM);
        k_gemm<64,64,0><<<g64,256,0,stream>>>(mix + TC,   Wk, kb, nullptr, nullptr, nullptr, CDIM, CDIM);
        k_gemm<64,64,0><<<g64,256,0,stream>>>(mix + 2*TC, Wv, vb, nullptr, nullptr, nullptr, CDIM, CDIM);
        k_gemm<64,64,0><<<g64,256,0,stream>>>(mix + 3*TC, Wg, gb, nullptr, nullptr, nullptr, CDIM, CDIM);
        k_wkv1<<<NCH * HNUM, 256, 0, stream>>>(kb, vb, dec, Stil);
        k_wkv2<<<HNUM, 256, 0, stream>>>(Stil, dec, S0);
        k_wkv3<<<NCH * HNUM, 256, 0, stream>>>(rb, kb, vb, S0, dec, bon, wkvo);
        k_gn_gate<<<T_LEN, 768, 0, stream>>>(wkvo, gb, tm_gn + (size_t)l * 2 * CDIM, y);
        k_gemm<64,64,1><<<g64,256,0,stream>>>(y, Wo, x, nullptr, x, nullptr, CDIM, CDIM);

        // ---- channel mixer ----
        k_ln<float><<<T_LEN, 256, 0, stream>>>(x, cm_ln + (size_t)l * 2 * CDIM, xn);
        k_lerp<2><<<T_LEN, 256, 0, stream>>>(xn, cm_ts + (size_t)l * 2 * CDIM, mix);
        k_gemm<64,64,0><<<g64,256,0,stream>>>(mix + TC, Wcg, gb, nullptr, nullptr, nullptr, CDIM, CDIM);
        k_gemm<128,128,2><<<gWin,256,0,stream>>>(mix, Win, nullptr, hb, nullptr, nullptr, FDIM, CDIM);
        k_gemm<64,64,3><<<g64,256,0,stream>>>(hb, Wou, x, nullptr, x, gb, CDIM, FDIM);
    }

    k_ln<ushort><<<T_LEN, 256, 0, stream>>>(x, head_ln, mix);
    k_gemm<128,128,0><<<gHead,256,0,stream>>>(mix, unembed, out, nullptr, nullptr, nullptr, VDIM, CDIM);
}

// Round 2
// 1190.280 us; speedup vs baseline: 1.7029x; 1.7029x over previous
//
#include <hip/hip_runtime.h>
#include <hip/hip_bf16.h>

#define T_LEN 1024
#define CDIM  768
#define HNUM  12
#define KDIM  64
#define LNUM  6
#define FDIM  2688
#define VDIM  50304
#define NCH   16     // wkv chunks
#define LCH   64     // chunk length

#define WSZ   (CDIM * CDIM)            // 589824
#define WIN_OFF  (6 * WSZ)             // 3538944
#define WOUT_OFF (WIN_OFF + CDIM * FDIM) // 5603328
#define WBUF_ELEMS (WOUT_OFF + FDIM * CDIM)

typedef __attribute__((ext_vector_type(4))) float f32x4;
typedef __attribute__((ext_vector_type(8))) short s16x8;

__device__ __forceinline__ ushort f2bf(float f) {
    union { float fv; unsigned u; } v; v.fv = f;
    unsigned r = v.u + 0x7fffu + ((v.u >> 16) & 1u);   // RNE
    return (ushort)(r >> 16);
}

__device__ __forceinline__ void gload_lds16(const ushort* g, ushort* l) {
    __builtin_amdgcn_global_load_lds(
        (const __attribute__((address_space(1))) void*)g,
        (__attribute__((address_space(3))) void*)l, 16, 0, 0);
}

// ---------------- transpose + f32->bf16 convert: out[n][k] = bf16(in[k][n]) ----
// R = rows of in (K dim), C = cols of in (N dim). One 64x64 tile per call.
__device__ __forceinline__ void trans_tile(const float* __restrict__ in,
        ushort* __restrict__ out, int R, int C, int tk, int tn) {
    __shared__ float tile[64][65];
    int tid = threadIdx.x;
    int r = tid >> 4, c4 = (tid & 15) << 2;
    int k0 = tk << 6, n0 = tn << 6;
    #pragma unroll
    for (int j = 0; j < 4; j++) {
        int rr = r + j * 16;
        float4 f = *(const float4*)&in[(size_t)(k0 + rr) * C + n0 + c4];
        tile[rr][c4 + 0] = f.x; tile[rr][c4 + 1] = f.y;
        tile[rr][c4 + 2] = f.z; tile[rr][c4 + 3] = f.w;
    }
    __syncthreads();
    #pragma unroll
    for (int j = 0; j < 4; j++) {
        int n = r + j * 16;
        ushort4 u;
        u.x = f2bf(tile[c4 + 0][n]);
        u.y = f2bf(tile[c4 + 1][n]);
        u.z = f2bf(tile[c4 + 2][n]);
        u.w = f2bf(tile[c4 + 3][n]);
        *(ushort4*)&out[(size_t)(n0 + n) * R + k0 + c4] = u;
    }
}

__global__ __launch_bounds__(256)
void k_trans(const float* __restrict__ in, ushort* __restrict__ out, int R, int C) {
    trans_tile(in, out, R, C, blockIdx.y, blockIdx.x);
}

// one layer's 8 weight matrices in a single launch (1872 tiles)
__global__ __launch_bounds__(256)
void k_conv_layer(const float* p0, const float* p1, const float* p2,
                  const float* p3, const float* p4, const float* p5,
                  const float* pWin, const float* pWout, ushort* wbuf) {
    int b = blockIdx.x;
    const float* in; ushort* out; int R, C, tk, tn;
    if (b < 864) {
        int mi = b / 144, t = b % 144;
        switch (mi) {
            case 0: in = p0; break; case 1: in = p1; break;
            case 2: in = p2; break; case 3: in = p3; break;
            case 4: in = p4; break; default: in = p5; break;
        }
        out = wbuf + (size_t)mi * WSZ; R = 768; C = 768;
        tk = t / 12; tn = t % 12;
    } else if (b < 1368) {
        int t = b - 864;
        in = pWin; out = wbuf + WIN_OFF; R = 768; C = 2688;
        tk = t / 42; tn = t % 42;
    } else {
        int t = b - 1368;
        in = pWout; out = wbuf + WOUT_OFF; R = 2688; C = 768;
        tk = t / 12; tn = t % 12;
    }
    trans_tile(in, out, R, C, tk, tn);
}

// ---------------- LayerNorm over C=768 -> bf16 (head input) ----------------
__global__ __launch_bounds__(256)
void k_ln_bf(const float* __restrict__ x, const float* __restrict__ wb,
             ushort* __restrict__ out) {
    int t = blockIdx.x, tid = threadIdx.x;
    float v[3]; float s = 0.f, s2 = 0.f;
    #pragma unroll
    for (int j = 0; j < 3; j++) {
        v[j] = x[(size_t)t * CDIM + tid + j * 256];
        s += v[j]; s2 += v[j] * v[j];
    }
    #pragma unroll
    for (int m = 32; m; m >>= 1) { s += __shfl_xor(s, m); s2 += __shfl_xor(s2, m); }
    __shared__ float rs[4], rq[4];
    int w = tid >> 6;
    if ((tid & 63) == 0) { rs[w] = s; rq[w] = s2; }
    __syncthreads();
    s = rs[0] + rs[1] + rs[2] + rs[3];
    s2 = rq[0] + rq[1] + rq[2] + rq[3];
    float mu = s * (1.f / CDIM);
    float inv = rsqrtf(s2 * (1.f / CDIM) - mu * mu + 1e-5f);
    #pragma unroll
    for (int j = 0; j < 3; j++) {
        int c = tid + j * 256;
        out[(size_t)t * CDIM + c] = f2bf((v[j] - mu) * inv * wb[c] + wb[CDIM + c]);
    }
}

// ---------------- embed lookup + LN -> f32 residual stream ----------------
__global__ __launch_bounds__(256)
void k_embed_ln(const int* __restrict__ tok, const float* __restrict__ embed,
                const float* __restrict__ wb, float* __restrict__ xout) {
    int t = blockIdx.x, tid = threadIdx.x;
    const float* row = embed + (size_t)tok[t] * CDIM;
    float v[3]; float s = 0.f, s2 = 0.f;
    #pragma unroll
    for (int j = 0; j < 3; j++) {
        v[j] = row[tid + j * 256]; s += v[j]; s2 += v[j] * v[j];
    }
    #pragma unroll
    for (int m = 32; m; m >>= 1) { s += __shfl_xor(s, m); s2 += __shfl_xor(s2, m); }
    __shared__ float rs[4], rq[4];
    int w = tid >> 6;
    if ((tid & 63) == 0) { rs[w] = s; rq[w] = s2; }
    __syncthreads();
    s = rs[0] + rs[1] + rs[2] + rs[3];
    s2 = rq[0] + rq[1] + rq[2] + rq[3];
    float mu = s * (1.f / CDIM);
    float inv = rsqrtf(s2 * (1.f / CDIM) - mu * mu + 1e-5f);
    #pragma unroll
    for (int j = 0; j < 3; j++) {
        int c = tid + j * 256;
        xout[(size_t)t * CDIM + c] = (v[j] - mu) * inv * wb[c] + wb[CDIM + c];
    }
}

// ---------------- fused LN + token-shift lerp -> NM bf16 mix buffers --------
template <int NM>
__global__ __launch_bounds__(256)
void k_lnlerp(const float* __restrict__ x, const float* __restrict__ lnw,
              const float* __restrict__ ts, ushort* __restrict__ mix) {
    int t = blockIdx.x, tid = threadIdx.x;
    bool has = (t > 0);
    float vb[3], va[3];
    float sb = 0.f, qb = 0.f, sa = 0.f, qa = 0.f;
    #pragma unroll
    for (int j = 0; j < 3; j++) {
        int c = tid + j * 256;
        vb[j] = x[(size_t)t * CDIM + c];
        sb += vb[j]; qb += vb[j] * vb[j];
        va[j] = has ? x[(size_t)(t - 1) * CDIM + c] : 0.f;
        sa += va[j]; qa += va[j] * va[j];
    }
    #pragma unroll
    for (int m = 32; m; m >>= 1) {
        sb += __shfl_xor(sb, m); qb += __shfl_xor(qb, m);
        sa += __shfl_xor(sa, m); qa += __shfl_xor(qa, m);
    }
    __shared__ float r0[4], r1[4], r2[4], r3[4];
    int w = tid >> 6;
    if ((tid & 63) == 0) { r0[w] = sb; r1[w] = qb; r2[w] = sa; r3[w] = qa; }
    __syncthreads();
    sb = r0[0] + r0[1] + r0[2] + r0[3]; qb = r1[0] + r1[1] + r1[2] + r1[3];
    sa = r2[0] + r2[1] + r2[2] + r2[3]; qa = r3[0] + r3[1] + r3[2] + r3[3];
    float mub = sb * (1.f / CDIM);
    float invb = rsqrtf(qb * (1.f / CDIM) - mub * mub + 1e-5f);
    float mua = sa * (1.f / CDIM);
    float inva = rsqrtf(qa * (1.f / CDIM) - mua * mua + 1e-5f);
    #pragma unroll
    for (int j = 0; j < 3; j++) {
        int c = tid + j * 256;
        float wgt = lnw[c], bia = lnw[CDIM + c];
        float xb = (vb[j] - mub) * invb * wgt + bia;
        float xa = has ? (va[j] - mua) * inva * wgt + bia : 0.f;
        #pragma unroll
        for (int m = 0; m < NM; m++) {
            float tv = ts[m * CDIM + c];
            mix[((size_t)m * T_LEN + t) * CDIM + c] = f2bf(xa + (xb - xa) * tv);
        }
    }
}

// ---------------- bf16 MFMA GEMM: C = A[M][K] @ Bt[N][K]^T ------------------
// Both operands bf16 row-major-in-K, staged via global_load_lds w=16 with the
// XOR swizzle applied in the per-lane GLOBAL source address (LDS stays linear).
// EPI: 0 = plain f32, 1 = resid+f32, 2 = relu^2 -> bf16, 3 = resid + v*sigmoid(gate)
template <int BM, int BN, int EPI, bool SWAP, bool BATCH>
__global__ __launch_bounds__(256)
void k_gemm_bf(const ushort* __restrict__ A, const ushort* __restrict__ Bt,
               float* __restrict__ Cf, ushort* __restrict__ Cb,
               const float* __restrict__ resid, const float* __restrict__ gate,
               int N, int K) {
    __shared__ __align__(16) ushort Al[BM * 32];
    __shared__ __align__(16) ushort Bl[BN * 32];
    const int tid = threadIdx.x, lane = tid & 63, wave = tid >> 6;
    if constexpr (BATCH) {
        int z = blockIdx.z;
        A  += (size_t)z * T_LEN * CDIM;
        Bt += (size_t)z * CDIM * CDIM;
        Cf += (size_t)z * T_LEN * CDIM;
    }
    const int mb = (SWAP ? blockIdx.x : blockIdx.y) * BM;
    const int nb = (SWAP ? blockIdx.y : blockIdx.x) * BN;
    constexpr int WM = BM / 2, WN = BN / 2, FM = WM / 16, FN = WN / 16;
    const int wm = (wave >> 1) * WM, wn = (wave & 1) * WN;
    constexpr int AR = (BM * 4) / 256;   // 16B slots per thread per tile
    constexpr int BR = (BN * 4) / 256;

    f32x4 acc[FM][FN];
    #pragma unroll
    for (int i = 0; i < FM; i++)
        #pragma unroll
        for (int j = 0; j < FN; j++) acc[i][j] = (f32x4)0.f;

    for (int k0 = 0; k0 < K; k0 += 32) {
        #pragma unroll
        for (int r = 0; r < AR; r++) {
            int slot = tid + r * 256;
            int row = slot >> 2, g = slot & 3;
            int gsrc = ((g ^ ((row >> 1) & 3)) << 3);
            gload_lds16(A + (size_t)(mb + row) * K + k0 + gsrc, &Al[slot * 8]);
        }
        #pragma unroll
        for (int r = 0; r < BR; r++) {
            int slot = tid + r * 256;
            int row = slot >> 2, g = slot & 3;
            int gsrc = ((g ^ ((row >> 1) & 3)) << 3);
            gload_lds16(Bt + (size_t)(nb + row) * K + k0 + gsrc, &Bl[slot * 8]);
        }
        __syncthreads();
        s16x8 af[FM], bfr[FN];
        const int kq = lane >> 4, ln15 = lane & 15;
        #pragma unroll
        for (int i = 0; i < FM; i++) {
            int row = wm + i * 16 + ln15;
            af[i] = *(const s16x8*)&Al[row * 32 + ((kq ^ ((row >> 1) & 3)) << 3)];
        }
        #pragma unroll
        for (int j = 0; j < FN; j++) {
            int row = wn + j * 16 + ln15;
            bfr[j] = *(const s16x8*)&Bl[row * 32 + ((kq ^ ((row >> 1) & 3)) << 3)];
        }
        #pragma unroll
        for (int i = 0; i < FM; i++)
            #pragma unroll
            for (int j = 0; j < FN; j++)
                acc[i][j] = __builtin_amdgcn_mfma_f32_16x16x32_bf16(
                    af[i], bfr[j], acc[i][j], 0, 0, 0);
        __syncthreads();
    }
    // epilogue: D row = (lane>>4)*4 + r, col = lane&15
    #pragma unroll
    for (int i = 0; i < FM; i++) {
        int rbase = mb + wm + i * 16 + (lane >> 4) * 4;
        #pragma unroll
        for (int j = 0; j < FN; j++) {
            int col = nb + wn + j * 16 + (lane & 15);
            #pragma unroll
            for (int r = 0; r < 4; r++) {
                size_t idx = (size_t)(rbase + r) * N + col;
                float vv = acc[i][j][r];
                if constexpr (EPI == 0) {
                    Cf[idx] = vv;
                } else if constexpr (EPI == 1) {
                    Cf[idx] = resid[idx] + vv;
                } else if constexpr (EPI == 2) {
                    float z = vv > 0.f ? vv * vv : 0.f;
                    Cb[idx] = f2bf(z);
                } else {
                    float gv = gate[idx];
                    Cf[idx] = resid[idx] + vv / (1.f + __expf(-gv));
                }
            }
        }
    }
}

// ---------------- WKV chunked scan ----------------
__global__ __launch_bounds__(256)
void k_wkv1(const float* __restrict__ kb, const float* __restrict__ vb,
            const float* __restrict__ decay, float* __restrict__ Stil) {
    int c = blockIdx.x / HNUM, h = blockIdx.x % HNUM;
    __shared__ float kl[4096], vl[4096], wsh[64];
    int tid = threadIdx.x;
    for (int idx = tid; idx < 4096; idx += 256) {
        int j = idx >> 6, cc = idx & 63;
        size_t g = (size_t)(c * LCH + j) * CDIM + h * 64 + cc;
        kl[idx] = kb[g]; vl[idx] = vb[g];
    }
    if (tid < 64) wsh[tid] = expf(-expf(decay[h * 64 + tid]));
    __syncthreads();
    int k = tid >> 2, v0 = (tid & 3) * 16;
    float w = wsh[k], f = 1.f;
    float s[16];
    #pragma unroll
    for (int i = 0; i < 16; i++) s[i] = 0.f;
    for (int j = 63; j >= 0; --j) {
        float kw = kl[j * 64 + k] * f;
        #pragma unroll
        for (int i = 0; i < 16; i++) s[i] += kw * vl[j * 64 + v0 + i];
        f *= w;
    }
    float* dst = Stil + ((size_t)(c * HNUM + h) << 12) + k * 64 + v0;
    #pragma unroll
    for (int i = 0; i < 16; i++) dst[i] = s[i];
}

__global__ __launch_bounds__(256)
void k_wkv2(const float* __restrict__ Stil, const float* __restrict__ decay,
            float* __restrict__ S0) {
    int h = blockIdx.x, tid = threadIdx.x;
    int k = tid >> 2, v0 = (tid & 3) * 16;
    float wLc = expf(-64.f * expf(decay[h * 64 + k]));   // w^64
    float s[16];
    #pragma unroll
    for (int i = 0; i < 16; i++) s[i] = 0.f;
    for (int c = 0; c < NCH; c++) {
        size_t base = ((size_t)(c * HNUM + h) << 12) + k * 64 + v0;
        float* dst = S0 + base;
        const float* src = Stil + base;
        #pragma unroll
        for (int i = 0; i < 16; i++) { dst[i] = s[i]; s[i] = s[i] * wLc + src[i]; }
    }
}

__global__ __launch_bounds__(256)
void k_wkv3(const float* __restrict__ rb, const float* __restrict__ kb,
            const float* __restrict__ vb, const float* __restrict__ S0,
            const float* __restrict__ decay, const float* __restrict__ bonus,
            float* __restrict__ outb) {
    int c = blockIdx.x / HNUM, h = blockIdx.x % HNUM;
    __shared__ float rl[4096], kl[4096], vl[4096], wsh[64], bsh[64];
    __shared__ float part[4][64];
    int tid = threadIdx.x;
    for (int idx = tid; idx < 4096; idx += 256) {
        int j = idx >> 6, cc = idx & 63;
        size_t g = (size_t)(c * LCH + j) * CDIM + h * 64 + cc;
        rl[idx] = rb[g]; kl[idx] = kb[g]; vl[idx] = vb[g];
    }
    if (tid < 64) {
        wsh[tid] = expf(-expf(decay[h * 64 + tid]));
        bsh[tid] = bonus[h * 64 + tid];
    }
    int v = tid & 63, kg = tid >> 6;
    float S[16];
    const float* s0p = S0 + ((size_t)(c * HNUM + h) << 12);
    #pragma unroll
    for (int i = 0; i < 16; i++) S[i] = s0p[(kg * 16 + i) * 64 + v];
    __syncthreads();
    for (int j = 0; j < 64; j++) {
        float vj = vl[j * 64 + v];
        float rsum = 0.f;
        #pragma unroll
        for (int i = 0; i < 16; i++) {
            int kk = kg * 16 + i;
            float a = kl[j * 64 + kk] * vj;
            rsum += rl[j * 64 + kk] * (S[i] + a * bsh[kk]);
            S[i] = S[i] * wsh[kk] + a;
        }
        part[kg][v] = rsum;
        __syncthreads();
        if (kg == 0)
            outb[(size_t)(c * LCH + j) * CDIM + h * 64 + v] =
                part[0][v] + part[1][v] + part[2][v] + part[3][v];
        __syncthreads();
    }
}

// ---------------- GroupNorm (per head of 64) * silu(g) -> bf16 --------------
__global__ __launch_bounds__(768)
void k_gn_gate(const float* __restrict__ xin, const float* __restrict__ g,
               const float* __restrict__ wb, ushort* __restrict__ y) {
    int t = blockIdx.x, c = threadIdx.x;
    float x = xin[(size_t)t * CDIM + c];
    float s = x, s2 = x * x;
    #pragma unroll
    for (int m = 32; m; m >>= 1) { s += __shfl_xor(s, m); s2 += __shfl_xor(s2, m); }
    float mu = s * (1.f / 64.f);
    float var = s2 * (1.f / 64.f) - mu * mu;
    float xg = (x - mu) * rsqrtf(var + 6.4e-4f);
    float gv = g[(size_t)t * CDIM + c];
    float silu = gv / (1.f + __expf(-gv));
    y[(size_t)t * CDIM + c] = f2bf((xg * wb[c] + wb[CDIM + c]) * silu);
}

// ---------------- host ----------------
extern "C" void kernel_launch(void* const* d_in, const int* in_sizes, int n_in,
                              void* d_out, int out_size, void* d_ws, size_t ws_size,
                              hipStream_t stream) {
    const int*   tok      = (const int*)d_in[0];
    const float* embed    = (const float*)d_in[1];
    const float* embed_ln = (const float*)d_in[2];
    const float* tm_ln    = (const float*)d_in[3];
    const float* tm_ts    = (const float*)d_in[4];
    const float* tm_Wr    = (const float*)d_in[5];
    const float* tm_Wk    = (const float*)d_in[6];
    const float* tm_Wv    = (const float*)d_in[7];
    const float* tm_Wg    = (const float*)d_in[8];
    const float* tm_Wo    = (const float*)d_in[9];
    const float* tm_bonus = (const float*)d_in[10];
    const float* tm_decay = (const float*)d_in[11];
    const float* tm_gn    = (const float*)d_in[12];
    const float* cm_ln    = (const float*)d_in[13];
    const float* cm_ts    = (const float*)d_in[14];
    const float* cm_Win   = (const float*)d_in[15];
    const float* cm_Wout  = (const float*)d_in[16];
    const float* cm_Wg    = (const float*)d_in[17];
    const float* head_ln  = (const float*)d_in[18];
    const float* unembed  = (const float*)d_in[19];
    float* out = (float*)d_out;

    const size_t TC = (size_t)T_LEN * CDIM;
    char* wp = (char*)d_ws;
    auto alloc = [&](size_t bytes) {
        char* p = wp; wp += (bytes + 255) & ~(size_t)255; return p;
    };
    float*  x    = (float*)alloc(TC * 4);
    ushort* mix  = (ushort*)alloc(4 * TC * 2);
    float*  rkvg = (float*)alloc(4 * TC * 4);
    float*  gcm  = (float*)alloc(TC * 4);
    float*  wkvo = (float*)alloc(TC * 4);
    ushort* y    = (ushort*)alloc(TC * 2);
    ushort* hb   = (ushort*)alloc((size_t)T_LEN * FDIM * 2);
    float*  Stil = (float*)alloc((size_t)NCH * HNUM * 4096 * 4);
    float*  S0   = (float*)alloc((size_t)NCH * HNUM * 4096 * 4);
    ushort* wbuf = (ushort*)alloc((size_t)WBUF_ELEMS * 2);
    ushort* ubuf = (ushort*)alloc((size_t)CDIM * VDIM * 2);
    if ((size_t)(wp - (char*)d_ws) > ws_size) return;   // fail loudly, no UB

    // unembed^T -> bf16 (needed only at the end; no deps)
    k_trans<<<dim3(VDIM / 64, CDIM / 64), 256, 0, stream>>>(unembed, ubuf, CDIM, VDIM);

    k_embed_ln<<<T_LEN, 256, 0, stream>>>(tok, embed, embed_ln, x);

    dim3 g64(CDIM / 64, T_LEN / 64);        // (12,16)
    dim3 gQKVG(CDIM / 64, T_LEN / 64, 4);   // (12,16,4)
    dim3 gWin(FDIM / 64, T_LEN / 64);       // (42,16)
    dim3 gHead(T_LEN / 128, VDIM / 128);    // (8,393) row-fastest (SWAP)

    for (int l = 0; l < LNUM; l++) {
        const size_t lo = (size_t)l * CDIM * CDIM;
        k_conv_layer<<<1872, 256, 0, stream>>>(
            tm_Wr + lo, tm_Wk + lo, tm_Wv + lo, tm_Wg + lo, tm_Wo + lo,
            cm_Wg + lo, cm_Win + (size_t)l * CDIM * FDIM,
            cm_Wout + (size_t)l * FDIM * CDIM, wbuf);
        const float* dec = tm_decay + (size_t)l * HNUM * KDIM;
        const float* bon = tm_bonus + (size_t)l * HNUM * KDIM;

        // ---- time mixer ----
        k_lnlerp<4><<<T_LEN, 256, 0, stream>>>(x, tm_ln + (size_t)l * 2 * CDIM,
                                               tm_ts + (size_t)l * 4 * CDIM, mix);
        k_gemm_bf<64,64,0,false,true><<<gQKVG, 256, 0, stream>>>(
            mix, wbuf, rkvg, nullptr, nullptr, nullptr, CDIM, CDIM);
        k_wkv1<<<NCH * HNUM, 256, 0, stream>>>(rkvg + TC, rkvg + 2 * TC, dec, Stil);
        k_wkv2<<<HNUM, 256, 0, stream>>>(Stil, dec, S0);
        k_wkv3<<<NCH * HNUM, 256, 0, stream>>>(rkvg, rkvg + TC, rkvg + 2 * TC,
                                               S0, dec, bon, wkvo);
        k_gn_gate<<<T_LEN, 768, 0, stream>>>(wkvo, rkvg + 3 * TC,
                                             tm_gn + (size_t)l * 2 * CDIM, y);
        k_gemm_bf<64,64,1,false,false><<<g64, 256, 0, stream>>>(
            y, wbuf + 4 * WSZ, x, nullptr, x, nullptr, CDIM, CDIM);

        // ---- channel mixer ----
        k_lnlerp<2><<<T_LEN, 256, 0, stream>>>(x, cm_ln + (size_t)l * 2 * CDIM,
                                               cm_ts + (size_t)l * 2 * CDIM, mix);
        k_gemm_bf<64,64,0,false,false><<<g64, 256, 0, stream>>>(
            mix + TC, wbuf + 5 * WSZ, gcm, nullptr, nullptr, nullptr, CDIM, CDIM);
        k_gemm_bf<64,64,2,false,false><<<gWin, 256, 0, stream>>>(
            mix, wbuf + WIN_OFF, nullptr, hb, nullptr, nullptr, FDIM, CDIM);
        k_gemm_bf<64,64,3,false,false><<<g64, 256, 0, stream>>>(
            hb, wbuf + WOUT_OFF, x, nullptr, x, gcm, CDIM, FDIM);
    }

    k_ln_bf<<<T_LEN, 256, 0, stream>>>(x, head_ln, mix);
    k_gemm_bf<128,128,0,true,false><<<gHead, 256, 0, stream>>>(
        mix, ubuf, out, nullptr, nullptr, nullptr, VDIM, CDIM);
}

// Round 3
// 1149.962 us; speedup vs baseline: 1.7626x; 1.0351x over previous
//
#include <hip/hip_runtime.h>
#include <hip/hip_bf16.h>

#define T_LEN 1024
#define CDIM  768
#define HNUM  12
#define KDIM  64
#define LNUM  6
#define FDIM  2688
#define VDIM  50304
#define NCH   16     // wkv chunks
#define LCH   64     // chunk length

#define WSZ   (CDIM * CDIM)              // 589824
#define WIN_OFF  (6 * WSZ)               // 3538944
#define WOUT_OFF (WIN_OFF + CDIM * FDIM) // 5603328
#define WBUF_ELEMS (WOUT_OFF + FDIM * CDIM)  // 7667712 elems per layer

typedef __attribute__((ext_vector_type(4))) float f32x4;
typedef __attribute__((ext_vector_type(8))) short s16x8;

__device__ __forceinline__ ushort f2bf(float f) {
    union { float fv; unsigned u; } v; v.fv = f;
    unsigned r = v.u + 0x7fffu + ((v.u >> 16) & 1u);   // RNE
    return (ushort)(r >> 16);
}

__device__ __forceinline__ void gload_lds16(const ushort* g, ushort* l) {
    __builtin_amdgcn_global_load_lds(
        (const __attribute__((address_space(1))) void*)g,
        (__attribute__((address_space(3))) void*)l, 16, 0, 0);
}

// ---------------- transpose + f32->bf16 convert: out[n][k] = bf16(in[k][n]) --
__device__ __forceinline__ void trans_tile(const float* __restrict__ in,
        ushort* __restrict__ out, int R, int C, int tk, int tn) {
    __shared__ float tile[64][65];
    int tid = threadIdx.x;
    int r = tid >> 4, c4 = (tid & 15) << 2;
    int k0 = tk << 6, n0 = tn << 6;
    #pragma unroll
    for (int j = 0; j < 4; j++) {
        int rr = r + j * 16;
        float4 f = *(const float4*)&in[(size_t)(k0 + rr) * C + n0 + c4];
        tile[rr][c4 + 0] = f.x; tile[rr][c4 + 1] = f.y;
        tile[rr][c4 + 2] = f.z; tile[rr][c4 + 3] = f.w;
    }
    __syncthreads();
    #pragma unroll
    for (int j = 0; j < 4; j++) {
        int n = r + j * 16;
        ushort4 u;
        u.x = f2bf(tile[c4 + 0][n]);
        u.y = f2bf(tile[c4 + 1][n]);
        u.z = f2bf(tile[c4 + 2][n]);
        u.w = f2bf(tile[c4 + 3][n]);
        *(ushort4*)&out[(size_t)(n0 + n) * R + k0 + c4] = u;
    }
}

__global__ __launch_bounds__(256)
void k_trans(const float* __restrict__ in, ushort* __restrict__ out, int R, int C) {
    trans_tile(in, out, R, C, blockIdx.y, blockIdx.x);
}

// per-layer tile mapping (1872 tiles)
__device__ __forceinline__ void conv_layer_tile(int t,
        const float* p0, const float* p1, const float* p2, const float* p3,
        const float* p4, const float* p5, const float* pWin, const float* pWout,
        ushort* wl) {
    const float* in; ushort* out; int R, C, tk, tn;
    if (t < 864) {
        int mi = t / 144, tt = t % 144;
        switch (mi) {
            case 0: in = p0; break; case 1: in = p1; break;
            case 2: in = p2; break; case 3: in = p3; break;
            case 4: in = p4; break; default: in = p5; break;
        }
        out = wl + (size_t)mi * WSZ; R = 768; C = 768;
        tk = tt / 12; tn = tt % 12;
    } else if (t < 1368) {
        int tt = t - 864;
        in = pWin; out = wl + WIN_OFF; R = 768; C = 2688;
        tk = tt / 42; tn = tt % 42;
    } else {
        int tt = t - 1368;
        in = pWout; out = wl + WOUT_OFF; R = 2688; C = 768;
        tk = tt / 12; tn = tt % 12;
    }
    trans_tile(in, out, R, C, tk, tn);
}

__global__ __launch_bounds__(256)
void k_conv_layer(const float* p0, const float* p1, const float* p2,
                  const float* p3, const float* p4, const float* p5,
                  const float* pWin, const float* pWout, ushort* wl) {
    conv_layer_tile(blockIdx.x, p0, p1, p2, p3, p4, p5, pWin, pWout, wl);
}

// all 6 layers + unembed in one launch (6*1872 + 9432 = 20664 blocks)
__global__ __launch_bounds__(256)
void k_conv_all(const float* Wr, const float* Wk, const float* Wv,
                const float* Wg, const float* Wo, const float* Wcg,
                const float* Win, const float* Wout, const float* unemb,
                ushort* wbuf, ushort* ubuf) {
    int b = blockIdx.x;
    if (b < 6 * 1872) {
        int l = b / 1872, t = b % 1872;
        conv_layer_tile(t,
            Wr + (size_t)l * WSZ, Wk + (size_t)l * WSZ, Wv + (size_t)l * WSZ,
            Wg + (size_t)l * WSZ, Wo + (size_t)l * WSZ, Wcg + (size_t)l * WSZ,
            Win + (size_t)l * CDIM * FDIM, Wout + (size_t)l * FDIM * CDIM,
            wbuf + (size_t)l * WBUF_ELEMS);
    } else {
        int t = b - 6 * 1872;              // 0..9431
        int tk = t / 786, tn = t % 786;    // R=768, C=VDIM
        trans_tile(unemb, ubuf, CDIM, VDIM, tk, tn);
    }
}

// ---------------- LayerNorm over C=768 -> bf16 (head input) ----------------
__global__ __launch_bounds__(256)
void k_ln_bf(const float* __restrict__ x, const float* __restrict__ wb,
             ushort* __restrict__ out) {
    int t = blockIdx.x, tid = threadIdx.x;
    float v[3]; float s = 0.f, s2 = 0.f;
    #pragma unroll
    for (int j = 0; j < 3; j++) {
        v[j] = x[(size_t)t * CDIM + tid + j * 256];
        s += v[j]; s2 += v[j] * v[j];
    }
    #pragma unroll
    for (int m = 32; m; m >>= 1) { s += __shfl_xor(s, m); s2 += __shfl_xor(s2, m); }
    __shared__ float rs[4], rq[4];
    int w = tid >> 6;
    if ((tid & 63) == 0) { rs[w] = s; rq[w] = s2; }
    __syncthreads();
    s = rs[0] + rs[1] + rs[2] + rs[3];
    s2 = rq[0] + rq[1] + rq[2] + rq[3];
    float mu = s * (1.f / CDIM);
    float inv = rsqrtf(s2 * (1.f / CDIM) - mu * mu + 1e-5f);
    #pragma unroll
    for (int j = 0; j < 3; j++) {
        int c = tid + j * 256;
        out[(size_t)t * CDIM + c] = f2bf((v[j] - mu) * inv * wb[c] + wb[CDIM + c]);
    }
}

// ---------------- embed lookup + LN -> f32 residual stream ----------------
__global__ __launch_bounds__(256)
void k_embed_ln(const int* __restrict__ tok, const float* __restrict__ embed,
                const float* __restrict__ wb, float* __restrict__ xout) {
    int t = blockIdx.x, tid = threadIdx.x;
    const float* row = embed + (size_t)tok[t] * CDIM;
    float v[3]; float s = 0.f, s2 = 0.f;
    #pragma unroll
    for (int j = 0; j < 3; j++) {
        v[j] = row[tid + j * 256]; s += v[j]; s2 += v[j] * v[j];
    }
    #pragma unroll
    for (int m = 32; m; m >>= 1) { s += __shfl_xor(s, m); s2 += __shfl_xor(s2, m); }
    __shared__ float rs[4], rq[4];
    int w = tid >> 6;
    if ((tid & 63) == 0) { rs[w] = s; rq[w] = s2; }
    __syncthreads();
    s = rs[0] + rs[1] + rs[2] + rs[3];
    s2 = rq[0] + rq[1] + rq[2] + rq[3];
    float mu = s * (1.f / CDIM);
    float inv = rsqrtf(s2 * (1.f / CDIM) - mu * mu + 1e-5f);
    #pragma unroll
    for (int j = 0; j < 3; j++) {
        int c = tid + j * 256;
        xout[(size_t)t * CDIM + c] = (v[j] - mu) * inv * wb[c] + wb[CDIM + c];
    }
}

// ---------------- fused LN + token-shift lerp -> NM bf16 mix buffers --------
template <int NM>
__global__ __launch_bounds__(256)
void k_lnlerp(const float* __restrict__ x, const float* __restrict__ lnw,
              const float* __restrict__ ts, ushort* __restrict__ mix) {
    int t = blockIdx.x, tid = threadIdx.x;
    bool has = (t > 0);
    float vb[3], va[3];
    float sb = 0.f, qb = 0.f, sa = 0.f, qa = 0.f;
    #pragma unroll
    for (int j = 0; j < 3; j++) {
        int c = tid + j * 256;
        vb[j] = x[(size_t)t * CDIM + c];
        sb += vb[j]; qb += vb[j] * vb[j];
        va[j] = has ? x[(size_t)(t - 1) * CDIM + c] : 0.f;
        sa += va[j]; qa += va[j] * va[j];
    }
    #pragma unroll
    for (int m = 32; m; m >>= 1) {
        sb += __shfl_xor(sb, m); qb += __shfl_xor(qb, m);
        sa += __shfl_xor(sa, m); qa += __shfl_xor(qa, m);
    }
    __shared__ float r0[4], r1[4], r2[4], r3[4];
    int w = tid >> 6;
    if ((tid & 63) == 0) { r0[w] = sb; r1[w] = qb; r2[w] = sa; r3[w] = qa; }
    __syncthreads();
    sb = r0[0] + r0[1] + r0[2] + r0[3]; qb = r1[0] + r1[1] + r1[2] + r1[3];
    sa = r2[0] + r2[1] + r2[2] + r2[3]; qa = r3[0] + r3[1] + r3[2] + r3[3];
    float mub = sb * (1.f / CDIM);
    float invb = rsqrtf(qb * (1.f / CDIM) - mub * mub + 1e-5f);
    float mua = sa * (1.f / CDIM);
    float inva = rsqrtf(qa * (1.f / CDIM) - mua * mua + 1e-5f);
    #pragma unroll
    for (int j = 0; j < 3; j++) {
        int c = tid + j * 256;
        float wgt = lnw[c], bia = lnw[CDIM + c];
        float xb = (vb[j] - mub) * invb * wgt + bia;
        float xa = has ? (va[j] - mua) * inva * wgt + bia : 0.f;
        #pragma unroll
        for (int m = 0; m < NM; m++) {
            float tv = ts[m * CDIM + c];
            mix[((size_t)m * T_LEN + t) * CDIM + c] = f2bf(xa + (xb - xa) * tv);
        }
    }
}

// ---------------- bf16 MFMA GEMM body: C = A[M][K] @ Bt[N][K]^T -------------
// EPI: 0 = f32, 1 = resid+f32, 2 = relu^2 -> bf16, 3 = resid + v*sigmoid(gate)
template <int BM, int BN, int EPI>
__device__ __forceinline__ void gemm_body(
        const ushort* __restrict__ A, const ushort* __restrict__ Bt,
        float* __restrict__ Cf, ushort* __restrict__ Cb,
        const float* __restrict__ resid, const float* __restrict__ gate,
        int N, int K, int mb, int nb, ushort* Al, ushort* Bl) {
    const int tid = threadIdx.x, lane = tid & 63, wave = tid >> 6;
    constexpr int WM = BM / 2, WN = BN / 2, FM = WM / 16, FN = WN / 16;
    const int wm = (wave >> 1) * WM, wn = (wave & 1) * WN;
    constexpr int AR = (BM * 4) / 256;   // 16B slots per thread per tile
    constexpr int BR = (BN * 4) / 256;

    f32x4 acc[FM][FN];
    #pragma unroll
    for (int i = 0; i < FM; i++)
        #pragma unroll
        for (int j = 0; j < FN; j++) acc[i][j] = (f32x4)0.f;

    for (int k0 = 0; k0 < K; k0 += 32) {
        #pragma unroll
        for (int r = 0; r < AR; r++) {
            int slot = tid + r * 256;
            int row = slot >> 2, g = slot & 3;
            int gsrc = ((g ^ ((row >> 1) & 3)) << 3);
            gload_lds16(A + (size_t)(mb + row) * K + k0 + gsrc, &Al[slot * 8]);
        }
        #pragma unroll
        for (int r = 0; r < BR; r++) {
            int slot = tid + r * 256;
            int row = slot >> 2, g = slot & 3;
            int gsrc = ((g ^ ((row >> 1) & 3)) << 3);
            gload_lds16(Bt + (size_t)(nb + row) * K + k0 + gsrc, &Bl[slot * 8]);
        }
        __syncthreads();
        s16x8 af[FM], bfr[FN];
        const int kq = lane >> 4, ln15 = lane & 15;
        #pragma unroll
        for (int i = 0; i < FM; i++) {
            int row = wm + i * 16 + ln15;
            af[i] = *(const s16x8*)&Al[row * 32 + ((kq ^ ((row >> 1) & 3)) << 3)];
        }
        #pragma unroll
        for (int j = 0; j < FN; j++) {
            int row = wn + j * 16 + ln15;
            bfr[j] = *(const s16x8*)&Bl[row * 32 + ((kq ^ ((row >> 1) & 3)) << 3)];
        }
        #pragma unroll
        for (int i = 0; i < FM; i++)
            #pragma unroll
            for (int j = 0; j < FN; j++)
                acc[i][j] = __builtin_amdgcn_mfma_f32_16x16x32_bf16(
                    af[i], bfr[j], acc[i][j], 0, 0, 0);
        __syncthreads();
    }
    #pragma unroll
    for (int i = 0; i < FM; i++) {
        int rbase = mb + wm + i * 16 + (lane >> 4) * 4;
        #pragma unroll
        for (int j = 0; j < FN; j++) {
            int col = nb + wn + j * 16 + (lane & 15);
            #pragma unroll
            for (int r = 0; r < 4; r++) {
                size_t idx = (size_t)(rbase + r) * N + col;
                float vv = acc[i][j][r];
                if constexpr (EPI == 0) {
                    Cf[idx] = vv;
                } else if constexpr (EPI == 1) {
                    Cf[idx] = resid[idx] + vv;
                } else if constexpr (EPI == 2) {
                    float z = vv > 0.f ? vv * vv : 0.f;
                    Cb[idx] = f2bf(z);
                } else {
                    float gv = gate[idx];
                    Cf[idx] = resid[idx] + vv / (1.f + __expf(-gv));
                }
            }
        }
    }
}

template <int BM, int BN, int EPI, bool BATCH>
__global__ __launch_bounds__(256)
void k_gemm_std(const ushort* __restrict__ A, const ushort* __restrict__ Bt,
                float* __restrict__ Cf, ushort* __restrict__ Cb,
                const float* __restrict__ resid, const float* __restrict__ gate,
                int N, int K) {
    __shared__ __align__(16) ushort Al[BM * 32];
    __shared__ __align__(16) ushort Bl[BN * 32];
    if constexpr (BATCH) {
        int z = blockIdx.z;
        A  += (size_t)z * T_LEN * CDIM;
        Bt += (size_t)z * CDIM * CDIM;
        Cf += (size_t)z * T_LEN * CDIM;
    }
    gemm_body<BM, BN, EPI>(A, Bt, Cf, Cb, resid, gate, N, K,
                           blockIdx.y * BM, blockIdx.x * BN, Al, Bl);
}

// head GEMM: XCD-aware mapping so the 8 mb-blocks of one nb-panel share an XCD L2
__global__ __launch_bounds__(256)
void k_gemm_head(const ushort* __restrict__ A, const ushort* __restrict__ Bt,
                 float* __restrict__ C) {
    __shared__ __align__(16) ushort Al[128 * 32];
    __shared__ __align__(16) ushort Bl[128 * 32];
    int id = blockIdx.x;
    int xcd = id & 7, slot = id >> 3;
    int mb = slot & 7, nbl = slot >> 3;
    int nb = nbl * 8 + xcd;                  // bijective, balanced
    if (nb >= VDIM / 128) return;
    gemm_body<128, 128, 0>(A, Bt, C, nullptr, nullptr, nullptr,
                           VDIM, CDIM, mb * 128, nb * 128, Al, Bl);
}

// channel-mixer Win (relu^2 -> hb) + Wcg (f32 gcm) merged in one launch
__global__ __launch_bounds__(256)
void k_cmix(const ushort* __restrict__ mix, const ushort* __restrict__ wl,
            ushort* __restrict__ hb, float* __restrict__ gcm) {
    __shared__ __align__(16) ushort Al[64 * 32];
    __shared__ __align__(16) ushort Bl[64 * 32];
    int bx = blockIdx.x, mb = blockIdx.y * 64;
    if (bx < FDIM / 64) {
        gemm_body<64, 64, 2>(mix, wl + WIN_OFF, nullptr, hb, nullptr, nullptr,
                             FDIM, CDIM, mb, bx * 64, Al, Bl);
    } else {
        gemm_body<64, 64, 0>(mix + (size_t)T_LEN * CDIM, wl + 5 * WSZ, gcm,
                             nullptr, nullptr, nullptr, CDIM, CDIM, mb,
                             (bx - FDIM / 64) * 64, Al, Bl);
    }
}

// ---------------- WKV chunked scan ----------------
__global__ __launch_bounds__(256)
void k_wkv1(const float* __restrict__ kb, const float* __restrict__ vb,
            const float* __restrict__ decay, float* __restrict__ Stil) {
    int c = blockIdx.x / HNUM, h = blockIdx.x % HNUM;
    __shared__ float kl[4096], vl[4096], wsh[64];
    int tid = threadIdx.x;
    for (int idx = tid; idx < 4096; idx += 256) {
        int j = idx >> 6, cc = idx & 63;
        size_t g = (size_t)(c * LCH + j) * CDIM + h * 64 + cc;
        kl[idx] = kb[g]; vl[idx] = vb[g];
    }
    if (tid < 64) wsh[tid] = expf(-expf(decay[h * 64 + tid]));
    __syncthreads();
    int k = tid >> 2, v0 = (tid & 3) * 16;
    float w = wsh[k], f = 1.f;
    float s[16];
    #pragma unroll
    for (int i = 0; i < 16; i++) s[i] = 0.f;
    for (int j = 63; j >= 0; --j) {
        float kw = kl[j * 64 + k] * f;
        #pragma unroll
        for (int i = 0; i < 16; i++) s[i] += kw * vl[j * 64 + v0 + i];
        f *= w;
    }
    float* dst = Stil + ((size_t)(c * HNUM + h) << 12) + k * 64 + v0;
    #pragma unroll
    for (int i = 0; i < 16; i++) dst[i] = s[i];
}

__global__ __launch_bounds__(256)
void k_wkv2(const float* __restrict__ Stil, const float* __restrict__ decay,
            float* __restrict__ S0) {
    int h = blockIdx.x, tid = threadIdx.x;
    int k = tid >> 2, v0 = (tid & 3) * 16;
    float wLc = expf(-64.f * expf(decay[h * 64 + k]));   // w^64
    float s[16];
    #pragma unroll
    for (int i = 0; i < 16; i++) s[i] = 0.f;
    for (int c = 0; c < NCH; c++) {
        size_t base = ((size_t)(c * HNUM + h) << 12) + k * 64 + v0;
        float* dst = S0 + base;
        const float* src = Stil + base;
        #pragma unroll
        for (int i = 0; i < 16; i++) { dst[i] = s[i]; s[i] = s[i] * wLc + src[i]; }
    }
}

// pass3 + fused GroupNorm*silu(gate) -> bf16 y. Barrier-free j-loop via part[].
__global__ __launch_bounds__(256)
void k_wkv3(const float* __restrict__ rb, const float* __restrict__ kb,
            const float* __restrict__ vb, const float* __restrict__ S0,
            const float* __restrict__ decay, const float* __restrict__ bonus,
            const float* __restrict__ gate, const float* __restrict__ gnw,
            ushort* __restrict__ y) {
    int c = blockIdx.x / HNUM, h = blockIdx.x % HNUM;
    __shared__ float rl[4096], kl[4096], vl[4096];
    __shared__ float part[4][4096];
    __shared__ float wsh[64], bsh[64];
    int tid = threadIdx.x;
    for (int idx = tid; idx < 4096; idx += 256) {
        int j = idx >> 6, cc = idx & 63;
        size_t g = (size_t)(c * LCH + j) * CDIM + h * 64 + cc;
        rl[idx] = rb[g]; kl[idx] = kb[g]; vl[idx] = vb[g];
    }
    if (tid < 64) {
        wsh[tid] = expf(-expf(decay[h * 64 + tid]));
        bsh[tid] = bonus[h * 64 + tid];
    }
    __syncthreads();
    int v = tid & 63, kg = tid >> 6;
    float S[16], wr[16], br[16];
    const float* s0p = S0 + ((size_t)(c * HNUM + h) << 12);
    #pragma unroll
    for (int i = 0; i < 16; i++) {
        S[i] = s0p[(kg * 16 + i) * 64 + v];
        wr[i] = wsh[kg * 16 + i];
        br[i] = bsh[kg * 16 + i];
    }
    for (int j = 0; j < 64; j++) {
        float vj = vl[j * 64 + v];
        const float4* kp = (const float4*)&kl[j * 64 + kg * 16];
        const float4* rp = (const float4*)&rl[j * 64 + kg * 16];
        float rsum = 0.f;
        #pragma unroll
        for (int q = 0; q < 4; q++) {
            float4 k4 = kp[q], r4 = rp[q];
            const float* kf = (const float*)&k4;
            const float* rf = (const float*)&r4;
            #pragma unroll
            for (int e = 0; e < 4; e++) {
                int i = q * 4 + e;
                float a = kf[e] * vj;
                rsum += rf[e] * (S[i] + a * br[i]);
                S[i] = S[i] * wr[i] + a;
            }
        }
        part[kg][j * 64 + v] = rsum;
    }
    __syncthreads();
    // epilogue: wave kg handles j = kg*16+jj; GroupNorm over 64 lanes + gate
    for (int jj = 0; jj < 16; jj++) {
        int j = kg * 16 + jj;
        float o = part[0][j * 64 + v] + part[1][j * 64 + v] +
                  part[2][j * 64 + v] + part[3][j * 64 + v];
        float s = o, s2 = o * o;
        #pragma unroll
        for (int m = 32; m; m >>= 1) { s += __shfl_xor(s, m); s2 += __shfl_xor(s2, m); }
        float mu = s * (1.f / 64.f);
        float var = s2 * (1.f / 64.f) - mu * mu;
        float xg = (o - mu) * rsqrtf(var + 6.4e-4f);
        int t = c * LCH + j, col = h * 64 + v;
        float gv = gate[(size_t)t * CDIM + col];
        float silu = gv / (1.f + __expf(-gv));
        y[(size_t)t * CDIM + col] = f2bf((xg * gnw[col] + gnw[CDIM + col]) * silu);
    }
}

// ---------------- host ----------------
extern "C" void kernel_launch(void* const* d_in, const int* in_sizes, int n_in,
                              void* d_out, int out_size, void* d_ws, size_t ws_size,
                              hipStream_t stream) {
    const int*   tok      = (const int*)d_in[0];
    const float* embed    = (const float*)d_in[1];
    const float* embed_ln = (const float*)d_in[2];
    const float* tm_ln    = (const float*)d_in[3];
    const float* tm_ts    = (const float*)d_in[4];
    const float* tm_Wr    = (const float*)d_in[5];
    const float* tm_Wk    = (const float*)d_in[6];
    const float* tm_Wv    = (const float*)d_in[7];
    const float* tm_Wg    = (const float*)d_in[8];
    const float* tm_Wo    = (const float*)d_in[9];
    const float* tm_bonus = (const float*)d_in[10];
    const float* tm_decay = (const float*)d_in[11];
    const float* tm_gn    = (const float*)d_in[12];
    const float* cm_ln    = (const float*)d_in[13];
    const float* cm_ts    = (const float*)d_in[14];
    const float* cm_Win   = (const float*)d_in[15];
    const float* cm_Wout  = (const float*)d_in[16];
    const float* cm_Wg    = (const float*)d_in[17];
    const float* head_ln  = (const float*)d_in[18];
    const float* unembed  = (const float*)d_in[19];
    float* out = (float*)d_out;

    const size_t TC = (size_t)T_LEN * CDIM;
    char* wp = (char*)d_ws;
    auto alloc = [&](size_t bytes) {
        char* p = wp; wp += (bytes + 255) & ~(size_t)255; return p;
    };
    float*  x    = (float*)alloc(TC * 4);
    ushort* mix  = (ushort*)alloc(4 * TC * 2);
    float*  rkvg = (float*)alloc(4 * TC * 4);
    float*  gcm  = (float*)alloc(TC * 4);
    ushort* y    = (ushort*)alloc(TC * 2);
    ushort* hb   = (ushort*)alloc((size_t)T_LEN * FDIM * 2);
    float*  Stil = (float*)alloc((size_t)NCH * HNUM * 4096 * 4);
    float*  S0   = (float*)alloc((size_t)NCH * HNUM * 4096 * 4);
    ushort* ubuf = (ushort*)alloc((size_t)CDIM * VDIM * 2);
    size_t fixed_bytes = (size_t)(wp - (char*)d_ws);
    const size_t per_layer = ((size_t)WBUF_ELEMS * 2 + 255) & ~(size_t)255;
    bool all6 = (fixed_bytes + 6 * per_layer) <= ws_size;
    ushort* wbuf = (ushort*)alloc(all6 ? 6 * per_layer : per_layer);
    if ((size_t)(wp - (char*)d_ws) > ws_size) return;   // fail loudly, no UB

    if (all6) {
        k_conv_all<<<6 * 1872 + 9432, 256, 0, stream>>>(
            tm_Wr, tm_Wk, tm_Wv, tm_Wg, tm_Wo, cm_Wg, cm_Win, cm_Wout,
            unembed, wbuf, ubuf);
    } else {
        k_trans<<<dim3(VDIM / 64, CDIM / 64), 256, 0, stream>>>(
            unembed, ubuf, CDIM, VDIM);
    }
    k_embed_ln<<<T_LEN, 256, 0, stream>>>(tok, embed, embed_ln, x);

    dim3 g64(CDIM / 64, T_LEN / 64);        // (12,16)
    dim3 gQKVG(CDIM / 64, T_LEN / 64, 4);   // (12,16,4)
    dim3 gCmix(FDIM / 64 + CDIM / 64, T_LEN / 64);  // (54,16)

    for (int l = 0; l < LNUM; l++) {
        ushort* wl = all6 ? (ushort*)((char*)wbuf + (size_t)l * per_layer) : wbuf;
        if (!all6) {
            const size_t lo = (size_t)l * CDIM * CDIM;
            k_conv_layer<<<1872, 256, 0, stream>>>(
                tm_Wr + lo, tm_Wk + lo, tm_Wv + lo, tm_Wg + lo, tm_Wo + lo,
                cm_Wg + lo, cm_Win + (size_t)l * CDIM * FDIM,
                cm_Wout + (size_t)l * FDIM * CDIM, wl);
        }
        const float* dec = tm_decay + (size_t)l * HNUM * KDIM;
        const float* bon = tm_bonus + (size_t)l * HNUM * KDIM;

        // ---- time mixer ----
        k_lnlerp<4><<<T_LEN, 256, 0, stream>>>(x, tm_ln + (size_t)l * 2 * CDIM,
                                               tm_ts + (size_t)l * 4 * CDIM, mix);
        k_gemm_std<64,64,0,true><<<gQKVG, 256, 0, stream>>>(
            mix, wl, rkvg, nullptr, nullptr, nullptr, CDIM, CDIM);
        k_wkv1<<<NCH * HNUM, 256, 0, stream>>>(rkvg + TC, rkvg + 2 * TC, dec, Stil);
        k_wkv2<<<HNUM, 256, 0, stream>>>(Stil, dec, S0);
        k_wkv3<<<NCH * HNUM, 256, 0, stream>>>(rkvg, rkvg + TC, rkvg + 2 * TC,
            S0, dec, bon, rkvg + 3 * TC, tm_gn + (size_t)l * 2 * CDIM, y);
        k_gemm_std<64,64,1,false><<<g64, 256, 0, stream>>>(
            y, wl + 4 * WSZ, x, nullptr, x, nullptr, CDIM, CDIM);

        // ---- channel mixer ----
        k_lnlerp<2><<<T_LEN, 256, 0, stream>>>(x, cm_ln + (size_t)l * 2 * CDIM,
                                               cm_ts + (size_t)l * 2 * CDIM, mix);
        k_cmix<<<gCmix, 256, 0, stream>>>(mix, wl, hb, gcm);
        k_gemm_std<64,64,3,false><<<g64, 256, 0, stream>>>(
            hb, wl + WOUT_OFF, x, nullptr, x, gcm, CDIM, FDIM);
    }

    k_ln_bf<<<T_LEN, 256, 0, stream>>>(x, head_ln, mix);
    k_gemm_head<<<3200, 256, 0, stream>>>(mix, ubuf, out);
}

// Round 4
// 1023.996 us; speedup vs baseline: 1.9794x; 1.1230x over previous
//
#include <hip/hip_runtime.h>
#include <hip/hip_bf16.h>

#define T_LEN 1024
#define CDIM  768
#define HNUM  12
#define KDIM  64
#define LNUM  6
#define FDIM  2688
#define VDIM  50304
#define NCH   16     // wkv chunks
#define LCH   64     // chunk length

#define WSZ   (CDIM * CDIM)              // 589824
#define WIN_OFF  (6 * WSZ)               // 3538944
#define WOUT_OFF (WIN_OFF + CDIM * FDIM) // 5603328
#define WBUF_ELEMS (WOUT_OFF + FDIM * CDIM)  // 7667712 elems per layer

typedef __attribute__((ext_vector_type(4))) float f32x4;
typedef __attribute__((ext_vector_type(8))) short s16x8;

__device__ __forceinline__ ushort f2bf(float f) {
    union { float fv; unsigned u; } v; v.fv = f;
    unsigned r = v.u + 0x7fffu + ((v.u >> 16) & 1u);   // RNE
    return (ushort)(r >> 16);
}

__device__ __forceinline__ void gload_lds16(const ushort* g, ushort* l) {
    __builtin_amdgcn_global_load_lds(
        (const __attribute__((address_space(1))) void*)g,
        (__attribute__((address_space(3))) void*)l, 16, 0, 0);
}

// ---------------- transpose + f32->bf16 convert: out[n][k] = bf16(in[k][n]) --
__device__ __forceinline__ void trans_tile(const float* __restrict__ in,
        ushort* __restrict__ out, int R, int C, int tk, int tn) {
    __shared__ float tile[64][65];
    int tid = threadIdx.x;
    int r = tid >> 4, c4 = (tid & 15) << 2;
    int k0 = tk << 6, n0 = tn << 6;
    #pragma unroll
    for (int j = 0; j < 4; j++) {
        int rr = r + j * 16;
        float4 f = *(const float4*)&in[(size_t)(k0 + rr) * C + n0 + c4];
        tile[rr][c4 + 0] = f.x; tile[rr][c4 + 1] = f.y;
        tile[rr][c4 + 2] = f.z; tile[rr][c4 + 3] = f.w;
    }
    __syncthreads();
    #pragma unroll
    for (int j = 0; j < 4; j++) {
        int n = r + j * 16;
        ushort4 u;
        u.x = f2bf(tile[c4 + 0][n]);
        u.y = f2bf(tile[c4 + 1][n]);
        u.z = f2bf(tile[c4 + 2][n]);
        u.w = f2bf(tile[c4 + 3][n]);
        *(ushort4*)&out[(size_t)(n0 + n) * R + k0 + c4] = u;
    }
}

__global__ __launch_bounds__(256)
void k_trans(const float* __restrict__ in, ushort* __restrict__ out, int R, int C) {
    trans_tile(in, out, R, C, blockIdx.y, blockIdx.x);
}

// per-layer tile mapping (1872 tiles)
__device__ __forceinline__ void conv_layer_tile(int t,
        const float* p0, const float* p1, const float* p2, const float* p3,
        const float* p4, const float* p5, const float* pWin, const float* pWout,
        ushort* wl) {
    const float* in; ushort* out; int R, C, tk, tn;
    if (t < 864) {
        int mi = t / 144, tt = t % 144;
        switch (mi) {
            case 0: in = p0; break; case 1: in = p1; break;
            case 2: in = p2; break; case 3: in = p3; break;
            case 4: in = p4; break; default: in = p5; break;
        }
        out = wl + (size_t)mi * WSZ; R = 768; C = 768;
        tk = tt / 12; tn = tt % 12;
    } else if (t < 1368) {
        int tt = t - 864;
        in = pWin; out = wl + WIN_OFF; R = 768; C = 2688;
        tk = tt / 42; tn = tt % 42;
    } else {
        int tt = t - 1368;
        in = pWout; out = wl + WOUT_OFF; R = 2688; C = 768;
        tk = tt / 12; tn = tt % 12;
    }
    trans_tile(in, out, R, C, tk, tn);
}

__global__ __launch_bounds__(256)
void k_conv_layer(const float* p0, const float* p1, const float* p2,
                  const float* p3, const float* p4, const float* p5,
                  const float* pWin, const float* pWout, ushort* wl) {
    conv_layer_tile(blockIdx.x, p0, p1, p2, p3, p4, p5, pWin, pWout, wl);
}

// all 6 layers + unembed in one launch (6*1872 + 9432 = 20664 blocks)
__global__ __launch_bounds__(256)
void k_conv_all(const float* Wr, const float* Wk, const float* Wv,
                const float* Wg, const float* Wo, const float* Wcg,
                const float* Win, const float* Wout, const float* unemb,
                ushort* wbuf, ushort* ubuf) {
    int b = blockIdx.x;
    if (b < 6 * 1872) {
        int l = b / 1872, t = b % 1872;
        conv_layer_tile(t,
            Wr + (size_t)l * WSZ, Wk + (size_t)l * WSZ, Wv + (size_t)l * WSZ,
            Wg + (size_t)l * WSZ, Wo + (size_t)l * WSZ, Wcg + (size_t)l * WSZ,
            Win + (size_t)l * CDIM * FDIM, Wout + (size_t)l * FDIM * CDIM,
            wbuf + (size_t)l * WBUF_ELEMS);
    } else {
        int t = b - 6 * 1872;              // 0..9431
        int tk = t / 786, tn = t % 786;    // R=768, C=VDIM
        trans_tile(unemb, ubuf, CDIM, VDIM, tk, tn);
    }
}

// ---------------- LayerNorm over C=768 -> bf16 (head input) ----------------
__global__ __launch_bounds__(256)
void k_ln_bf(const float* __restrict__ x, const float* __restrict__ wb,
             ushort* __restrict__ out) {
    int t = blockIdx.x, tid = threadIdx.x;
    float v[3]; float s = 0.f, s2 = 0.f;
    #pragma unroll
    for (int j = 0; j < 3; j++) {
        v[j] = x[(size_t)t * CDIM + tid + j * 256];
        s += v[j]; s2 += v[j] * v[j];
    }
    #pragma unroll
    for (int m = 32; m; m >>= 1) { s += __shfl_xor(s, m); s2 += __shfl_xor(s2, m); }
    __shared__ float rs[4], rq[4];
    int w = tid >> 6;
    if ((tid & 63) == 0) { rs[w] = s; rq[w] = s2; }
    __syncthreads();
    s = rs[0] + rs[1] + rs[2] + rs[3];
    s2 = rq[0] + rq[1] + rq[2] + rq[3];
    float mu = s * (1.f / CDIM);
    float inv = rsqrtf(s2 * (1.f / CDIM) - mu * mu + 1e-5f);
    #pragma unroll
    for (int j = 0; j < 3; j++) {
        int c = tid + j * 256;
        out[(size_t)t * CDIM + c] = f2bf((v[j] - mu) * inv * wb[c] + wb[CDIM + c]);
    }
}

// ---------------- embed lookup + LN -> f32 residual stream ----------------
__global__ __launch_bounds__(256)
void k_embed_ln(const int* __restrict__ tok, const float* __restrict__ embed,
                const float* __restrict__ wb, float* __restrict__ xout) {
    int t = blockIdx.x, tid = threadIdx.x;
    const float* row = embed + (size_t)tok[t] * CDIM;
    float v[3]; float s = 0.f, s2 = 0.f;
    #pragma unroll
    for (int j = 0; j < 3; j++) {
        v[j] = row[tid + j * 256]; s += v[j]; s2 += v[j] * v[j];
    }
    #pragma unroll
    for (int m = 32; m; m >>= 1) { s += __shfl_xor(s, m); s2 += __shfl_xor(s2, m); }
    __shared__ float rs[4], rq[4];
    int w = tid >> 6;
    if ((tid & 63) == 0) { rs[w] = s; rq[w] = s2; }
    __syncthreads();
    s = rs[0] + rs[1] + rs[2] + rs[3];
    s2 = rq[0] + rq[1] + rq[2] + rq[3];
    float mu = s * (1.f / CDIM);
    float inv = rsqrtf(s2 * (1.f / CDIM) - mu * mu + 1e-5f);
    #pragma unroll
    for (int j = 0; j < 3; j++) {
        int c = tid + j * 256;
        xout[(size_t)t * CDIM + c] = (v[j] - mu) * inv * wb[c] + wb[CDIM + c];
    }
}

// ---------------- fused LN + token-shift lerp -> NM bf16 mix buffers --------
template <int NM>
__global__ __launch_bounds__(256)
void k_lnlerp(const float* __restrict__ x, const float* __restrict__ lnw,
              const float* __restrict__ ts, ushort* __restrict__ mix) {
    int t = blockIdx.x, tid = threadIdx.x;
    bool has = (t > 0);
    float vb[3], va[3];
    float sb = 0.f, qb = 0.f, sa = 0.f, qa = 0.f;
    #pragma unroll
    for (int j = 0; j < 3; j++) {
        int c = tid + j * 256;
        vb[j] = x[(size_t)t * CDIM + c];
        sb += vb[j]; qb += vb[j] * vb[j];
        va[j] = has ? x[(size_t)(t - 1) * CDIM + c] : 0.f;
        sa += va[j]; qa += va[j] * va[j];
    }
    #pragma unroll
    for (int m = 32; m; m >>= 1) {
        sb += __shfl_xor(sb, m); qb += __shfl_xor(qb, m);
        sa += __shfl_xor(sa, m); qa += __shfl_xor(qa, m);
    }
    __shared__ float r0[4], r1[4], r2[4], r3[4];
    int w = tid >> 6;
    if ((tid & 63) == 0) { r0[w] = sb; r1[w] = qb; r2[w] = sa; r3[w] = qa; }
    __syncthreads();
    sb = r0[0] + r0[1] + r0[2] + r0[3]; qb = r1[0] + r1[1] + r1[2] + r1[3];
    sa = r2[0] + r2[1] + r2[2] + r2[3]; qa = r3[0] + r3[1] + r3[2] + r3[3];
    float mub = sb * (1.f / CDIM);
    float invb = rsqrtf(qb * (1.f / CDIM) - mub * mub + 1e-5f);
    float mua = sa * (1.f / CDIM);
    float inva = rsqrtf(qa * (1.f / CDIM) - mua * mua + 1e-5f);
    #pragma unroll
    for (int j = 0; j < 3; j++) {
        int c = tid + j * 256;
        float wgt = lnw[c], bia = lnw[CDIM + c];
        float xb = (vb[j] - mub) * invb * wgt + bia;
        float xa = has ? (va[j] - mua) * inva * wgt + bia : 0.f;
        #pragma unroll
        for (int m = 0; m < NM; m++) {
            float tv = ts[m * CDIM + c];
            mix[((size_t)m * T_LEN + t) * CDIM + c] = f2bf(xa + (xb - xa) * tv);
        }
    }
}

// ---------------- bf16 MFMA GEMM body: C = A[M][K] @ Bt[N][K]^T -------------
// BK=64, double-buffered LDS, 2-phase pipeline (stage t+1 || compute t).
// XOR swizzle on 16B groups applied via pre-swizzled GLOBAL source address.
// EPI: 0 = f32, 1 = resid+f32, 2 = relu^2 -> bf16, 3 = resid + v*sigmoid(gate)
template <int BM, int BN, int EPI>
__device__ __forceinline__ void gemm_body(
        const ushort* __restrict__ A, const ushort* __restrict__ Bt,
        float* __restrict__ Cf, ushort* __restrict__ Cb,
        const float* __restrict__ resid, const float* __restrict__ gate,
        int N, int K, int mb, int nb, ushort* Al, ushort* Bl) {
    const int tid = threadIdx.x, lane = tid & 63, wave = tid >> 6;
    constexpr int WM = BM / 2, WN = BN / 2, FM = WM / 16, FN = WN / 16;
    const int wm = (wave >> 1) * WM, wn = (wave & 1) * WN;
    constexpr int AR = (BM * 8) / 256;   // 16B slots per thread (BK=64)
    constexpr int BR = (BN * 8) / 256;

    auto stage = [&](int buf, int kt) {
        int k0 = kt << 6;
        #pragma unroll
        for (int r = 0; r < AR; r++) {
            int slot = tid + r * 256;
            int row = slot >> 3, g = slot & 7;
            int gk = ((g ^ (row & 7)) << 3);
            gload_lds16(A + (size_t)(mb + row) * K + k0 + gk,
                        &Al[buf * BM * 64 + slot * 8]);
        }
        #pragma unroll
        for (int r = 0; r < BR; r++) {
            int slot = tid + r * 256;
            int row = slot >> 3, g = slot & 7;
            int gk = ((g ^ (row & 7)) << 3);
            gload_lds16(Bt + (size_t)(nb + row) * K + k0 + gk,
                        &Bl[buf * BN * 64 + slot * 8]);
        }
    };

    f32x4 acc[FM][FN];
    #pragma unroll
    for (int i = 0; i < FM; i++)
        #pragma unroll
        for (int j = 0; j < FN; j++) acc[i][j] = (f32x4)0.f;

    const int nt = K >> 6;
    stage(0, 0);
    __syncthreads();                      // drain vmcnt: buf0 ready
    int cur = 0;
    for (int t = 0; t < nt; t++) {
        if (t + 1 < nt) stage(cur ^ 1, t + 1);   // issue next tile early
        const ushort* Ab = &Al[cur * BM * 64];
        const ushort* Bb = &Bl[cur * BN * 64];
        const int kq = lane >> 4, ln15 = lane & 15;
        #pragma unroll
        for (int s = 0; s < 2; s++) {
            s16x8 af[FM], bfr[FN];
            #pragma unroll
            for (int i = 0; i < FM; i++) {
                int row = wm + i * 16 + ln15;
                int g = (s * 4 + kq) ^ (row & 7);
                af[i] = *(const s16x8*)&Ab[row * 64 + g * 8];
            }
            #pragma unroll
            for (int j = 0; j < FN; j++) {
                int row = wn + j * 16 + ln15;
                int g = (s * 4 + kq) ^ (row & 7);
                bfr[j] = *(const s16x8*)&Bb[row * 64 + g * 8];
            }
            #pragma unroll
            for (int i = 0; i < FM; i++)
                #pragma unroll
                for (int j = 0; j < FN; j++)
                    acc[i][j] = __builtin_amdgcn_mfma_f32_16x16x32_bf16(
                        af[i], bfr[j], acc[i][j], 0, 0, 0);
        }
        __syncthreads();                  // drains next-tile stage + joins
        cur ^= 1;
    }
    #pragma unroll
    for (int i = 0; i < FM; i++) {
        int rbase = mb + wm + i * 16 + (lane >> 4) * 4;
        #pragma unroll
        for (int j = 0; j < FN; j++) {
            int col = nb + wn + j * 16 + (lane & 15);
            #pragma unroll
            for (int r = 0; r < 4; r++) {
                size_t idx = (size_t)(rbase + r) * N + col;
                float vv = acc[i][j][r];
                if constexpr (EPI == 0) {
                    Cf[idx] = vv;
                } else if constexpr (EPI == 1) {
                    Cf[idx] = resid[idx] + vv;
                } else if constexpr (EPI == 2) {
                    float z = vv > 0.f ? vv * vv : 0.f;
                    Cb[idx] = f2bf(z);
                } else {
                    float gv = gate[idx];
                    Cf[idx] = resid[idx] + vv / (1.f + __expf(-gv));
                }
            }
        }
    }
}

template <int BM, int BN, int EPI, bool BATCH>
__global__ __launch_bounds__(256)
void k_gemm_std(const ushort* __restrict__ A, const ushort* __restrict__ Bt,
                float* __restrict__ Cf, ushort* __restrict__ Cb,
                const float* __restrict__ resid, const float* __restrict__ gate,
                int N, int K) {
    __shared__ __align__(16) ushort Al[2 * BM * 64];
    __shared__ __align__(16) ushort Bl[2 * BN * 64];
    if constexpr (BATCH) {
        int z = blockIdx.z;
        A  += (size_t)z * T_LEN * CDIM;
        Bt += (size_t)z * CDIM * CDIM;
        Cf += (size_t)z * T_LEN * CDIM;
    }
    gemm_body<BM, BN, EPI>(A, Bt, Cf, Cb, resid, gate, N, K,
                           blockIdx.y * BM, blockIdx.x * BN, Al, Bl);
}

// head GEMM: XCD-aware mapping so the 8 mb-blocks of one nb-panel share an XCD L2
__global__ __launch_bounds__(256)
void k_gemm_head(const ushort* __restrict__ A, const ushort* __restrict__ Bt,
                 float* __restrict__ C) {
    __shared__ __align__(16) ushort Al[2 * 128 * 64];
    __shared__ __align__(16) ushort Bl[2 * 128 * 64];
    int id = blockIdx.x;
    int xcd = id & 7, slot = id >> 3;
    int mb = slot & 7, nbl = slot >> 3;
    int nb = nbl * 8 + xcd;                  // bijective, balanced
    if (nb >= VDIM / 128) return;
    gemm_body<128, 128, 0>(A, Bt, C, nullptr, nullptr, nullptr,
                           VDIM, CDIM, mb * 128, nb * 128, Al, Bl);
}

// channel-mixer Win (relu^2 -> hb) + Wcg (f32 gcm) merged in one launch
__global__ __launch_bounds__(256)
void k_cmix(const ushort* __restrict__ mix, const ushort* __restrict__ wl,
            ushort* __restrict__ hb, float* __restrict__ gcm) {
    __shared__ __align__(16) ushort Al[2 * 64 * 64];
    __shared__ __align__(16) ushort Bl[2 * 64 * 64];
    int bx = blockIdx.x, mb = blockIdx.y * 64;
    if (bx < FDIM / 64) {
        gemm_body<64, 64, 2>(mix, wl + WIN_OFF, nullptr, hb, nullptr, nullptr,
                             FDIM, CDIM, mb, bx * 64, Al, Bl);
    } else {
        gemm_body<64, 64, 0>(mix + (size_t)T_LEN * CDIM, wl + 5 * WSZ, gcm,
                             nullptr, nullptr, nullptr, CDIM, CDIM, mb,
                             (bx - FDIM / 64) * 64, Al, Bl);
    }
}

// ---------------- WKV chunked scan ----------------
// pass1: per-chunk local state  Stil[c][h][k][v] = sum_j w^(63-j) k_j[k] v_j[v]
__global__ __launch_bounds__(256)
void k_wkv1(const float* __restrict__ kb, const float* __restrict__ vb,
            const float* __restrict__ decay, float* __restrict__ Stil) {
    int c = blockIdx.x / HNUM, h = blockIdx.x % HNUM;
    __shared__ float kl[4096], vl[4096], wsh[64];
    int tid = threadIdx.x;
    for (int idx = tid; idx < 4096; idx += 256) {
        int j = idx >> 6, cc = idx & 63;
        size_t g = (size_t)(c * LCH + j) * CDIM + h * 64 + cc;
        kl[idx] = kb[g]; vl[idx] = vb[g];
    }
    if (tid < 64) wsh[tid] = expf(-expf(decay[h * 64 + tid]));
    __syncthreads();
    int k = tid >> 2, v0 = (tid & 3) * 16;
    float w = wsh[k], f = 1.f;
    float s[16];
    #pragma unroll
    for (int i = 0; i < 16; i++) s[i] = 0.f;
    for (int j = 63; j >= 0; --j) {
        float kw = kl[j * 64 + k] * f;
        #pragma unroll
        for (int i = 0; i < 16; i++) s[i] += kw * vl[j * 64 + v0 + i];
        f *= w;
    }
    float* dst = Stil + ((size_t)(c * HNUM + h) << 12) + k * 64 + v0;
    #pragma unroll
    for (int i = 0; i < 16; i++) dst[i] = s[i];
}

// pass2+3 merged: each (c,h) block computes its own chunk-prefix from Stil,
// then replays the chunk; fused GroupNorm*silu(gate) epilogue -> bf16 y.
__global__ __launch_bounds__(256)
void k_wkv23(const float* __restrict__ rb, const float* __restrict__ kb,
             const float* __restrict__ vb, const float* __restrict__ Stil,
             const float* __restrict__ decay, const float* __restrict__ bonus,
             const float* __restrict__ gate, const float* __restrict__ gnw,
             ushort* __restrict__ y) {
    int c = blockIdx.x / HNUM, h = blockIdx.x % HNUM;
    __shared__ float rl[4096], kl[4096], vl[4096];
    __shared__ float part[4][4096];
    __shared__ float wsh[64], bsh[64];
    int tid = threadIdx.x;
    for (int idx = tid; idx < 4096; idx += 256) {
        int j = idx >> 6, cc = idx & 63;
        size_t g = (size_t)(c * LCH + j) * CDIM + h * 64 + cc;
        rl[idx] = rb[g]; kl[idx] = kb[g]; vl[idx] = vb[g];
    }
    if (tid < 64) {
        wsh[tid] = expf(-expf(decay[h * 64 + tid]));
        bsh[tid] = bonus[h * 64 + tid];
    }
    __syncthreads();
    int v = tid & 63, kg = tid >> 6;
    float S[16], wr[16], br[16], w64[16];
    #pragma unroll
    for (int i = 0; i < 16; i++) {
        S[i] = 0.f;
        wr[i] = wsh[kg * 16 + i];
        br[i] = bsh[kg * 16 + i];
        float e = expf(decay[h * 64 + kg * 16 + i]);
        w64[i] = expf(-64.f * e);                    // w^64
    }
    for (int cc = 0; cc < c; cc++) {                 // chunk-prefix stitch
        const float* sp = Stil + ((size_t)(cc * HNUM + h) << 12);
        #pragma unroll
        for (int i = 0; i < 16; i++)
            S[i] = S[i] * w64[i] + sp[(kg * 16 + i) * 64 + v];
    }
    for (int j = 0; j < 64; j++) {
        float vj = vl[j * 64 + v];
        const float4* kp = (const float4*)&kl[j * 64 + kg * 16];
        const float4* rp = (const float4*)&rl[j * 64 + kg * 16];
        float rsum = 0.f;
        #pragma unroll
        for (int q = 0; q < 4; q++) {
            float4 k4 = kp[q], r4 = rp[q];
            const float* kf = (const float*)&k4;
            const float* rf = (const float*)&r4;
            #pragma unroll
            for (int e = 0; e < 4; e++) {
                int i = q * 4 + e;
                float a = kf[e] * vj;
                rsum += rf[e] * (S[i] + a * br[i]);
                S[i] = S[i] * wr[i] + a;
            }
        }
        part[kg][j * 64 + v] = rsum;
    }
    __syncthreads();
    // epilogue: wave kg handles j = kg*16+jj; GroupNorm over 64 lanes + gate
    for (int jj = 0; jj < 16; jj++) {
        int j = kg * 16 + jj;
        float o = part[0][j * 64 + v] + part[1][j * 64 + v] +
                  part[2][j * 64 + v] + part[3][j * 64 + v];
        float s = o, s2 = o * o;
        #pragma unroll
        for (int m = 32; m; m >>= 1) { s += __shfl_xor(s, m); s2 += __shfl_xor(s2, m); }
        float mu = s * (1.f / 64.f);
        float var = s2 * (1.f / 64.f) - mu * mu;
        float xg = (o - mu) * rsqrtf(var + 6.4e-4f);
        int t = c * LCH + j, col = h * 64 + v;
        float gv = gate[(size_t)t * CDIM + col];
        float silu = gv / (1.f + __expf(-gv));
        y[(size_t)t * CDIM + col] = f2bf((xg * gnw[col] + gnw[CDIM + col]) * silu);
    }
}

// ---------------- host ----------------
extern "C" void kernel_launch(void* const* d_in, const int* in_sizes, int n_in,
                              void* d_out, int out_size, void* d_ws, size_t ws_size,
                              hipStream_t stream) {
    const int*   tok      = (const int*)d_in[0];
    const float* embed    = (const float*)d_in[1];
    const float* embed_ln = (const float*)d_in[2];
    const float* tm_ln    = (const float*)d_in[3];
    const float* tm_ts    = (const float*)d_in[4];
    const float* tm_Wr    = (const float*)d_in[5];
    const float* tm_Wk    = (const float*)d_in[6];
    const float* tm_Wv    = (const float*)d_in[7];
    const float* tm_Wg    = (const float*)d_in[8];
    const float* tm_Wo    = (const float*)d_in[9];
    const float* tm_bonus = (const float*)d_in[10];
    const float* tm_decay = (const float*)d_in[11];
    const float* tm_gn    = (const float*)d_in[12];
    const float* cm_ln    = (const float*)d_in[13];
    const float* cm_ts    = (const float*)d_in[14];
    const float* cm_Win   = (const float*)d_in[15];
    const float* cm_Wout  = (const float*)d_in[16];
    const float* cm_Wg    = (const float*)d_in[17];
    const float* head_ln  = (const float*)d_in[18];
    const float* unembed  = (const float*)d_in[19];
    float* out = (float*)d_out;

    const size_t TC = (size_t)T_LEN * CDIM;
    char* wp = (char*)d_ws;
    auto alloc = [&](size_t bytes) {
        char* p = wp; wp += (bytes + 255) & ~(size_t)255; return p;
    };
    float*  x    = (float*)alloc(TC * 4);
    ushort* mix  = (ushort*)alloc(4 * TC * 2);
    float*  rkvg = (float*)alloc(4 * TC * 4);
    float*  gcm  = (float*)alloc(TC * 4);
    ushort* y    = (ushort*)alloc(TC * 2);
    ushort* hb   = (ushort*)alloc((size_t)T_LEN * FDIM * 2);
    float*  Stil = (float*)alloc((size_t)NCH * HNUM * 4096 * 4);
    ushort* ubuf = (ushort*)alloc((size_t)CDIM * VDIM * 2);
    size_t fixed_bytes = (size_t)(wp - (char*)d_ws);
    const size_t per_layer = ((size_t)WBUF_ELEMS * 2 + 255) & ~(size_t)255;
    bool all6 = (fixed_bytes + 6 * per_layer) <= ws_size;
    ushort* wbuf = (ushort*)alloc(all6 ? 6 * per_layer : per_layer);
    if ((size_t)(wp - (char*)d_ws) > ws_size) return;   // fail loudly, no UB

    if (all6) {
        k_conv_all<<<6 * 1872 + 9432, 256, 0, stream>>>(
            tm_Wr, tm_Wk, tm_Wv, tm_Wg, tm_Wo, cm_Wg, cm_Win, cm_Wout,
            unembed, wbuf, ubuf);
    } else {
        k_trans<<<dim3(VDIM / 64, CDIM / 64), 256, 0, stream>>>(
            unembed, ubuf, CDIM, VDIM);
    }
    k_embed_ln<<<T_LEN, 256, 0, stream>>>(tok, embed, embed_ln, x);

    dim3 g64(CDIM / 64, T_LEN / 64);        // (12,16)
    dim3 gQKVG(CDIM / 64, T_LEN / 64, 4);   // (12,16,4)
    dim3 gCmix(FDIM / 64 + CDIM / 64, T_LEN / 64);  // (54,16)

    for (int l = 0; l < LNUM; l++) {
        ushort* wl = all6 ? (ushort*)((char*)wbuf + (size_t)l * per_layer) : wbuf;
        if (!all6) {
            const size_t lo = (size_t)l * CDIM * CDIM;
            k_conv_layer<<<1872, 256, 0, stream>>>(
                tm_Wr + lo, tm_Wk + lo, tm_Wv + lo, tm_Wg + lo, tm_Wo + lo,
                cm_Wg + lo, cm_Win + (size_t)l * CDIM * FDIM,
                cm_Wout + (size_t)l * FDIM * CDIM, wl);
        }
        const float* dec = tm_decay + (size_t)l * HNUM * KDIM;
        const float* bon = tm_bonus + (size_t)l * HNUM * KDIM;

        // ---- time mixer ----
        k_lnlerp<4><<<T_LEN, 256, 0, stream>>>(x, tm_ln + (size_t)l * 2 * CDIM,
                                               tm_ts + (size_t)l * 4 * CDIM, mix);
        k_gemm_std<64,64,0,true><<<gQKVG, 256, 0, stream>>>(
            mix, wl, rkvg, nullptr, nullptr, nullptr, CDIM, CDIM);
        k_wkv1<<<NCH * HNUM, 256, 0, stream>>>(rkvg + TC, rkvg + 2 * TC, dec, Stil);
        k_wkv23<<<NCH * HNUM, 256, 0, stream>>>(rkvg, rkvg + TC, rkvg + 2 * TC,
            Stil, dec, bon, rkvg + 3 * TC, tm_gn + (size_t)l * 2 * CDIM, y);
        k_gemm_std<64,64,1,false><<<g64, 256, 0, stream>>>(
            y, wl + 4 * WSZ, x, nullptr, x, nullptr, CDIM, CDIM);

        // ---- channel mixer ----
        k_lnlerp<2><<<T_LEN, 256, 0, stream>>>(x, cm_ln + (size_t)l * 2 * CDIM,
                                               cm_ts + (size_t)l * 2 * CDIM, mix);
        k_cmix<<<gCmix, 256, 0, stream>>>(mix, wl, hb, gcm);
        k_gemm_std<64,64,3,false><<<g64, 256, 0, stream>>>(
            hb, wl + WOUT_OFF, x, nullptr, x, gcm, CDIM, FDIM);
    }

    k_ln_bf<<<T_LEN, 256, 0, stream>>>(x, head_ln, mix);
    k_gemm_head<<<3200, 256, 0, stream>>>(mix, ubuf, out);
}

// Round 5
// 965.977 us; speedup vs baseline: 2.0983x; 1.0601x over previous
//
#include <hip/hip_runtime.h>
#include <hip/hip_bf16.h>

#define T_LEN 1024
#define CDIM  768
#define HNUM  12
#define KDIM  64
#define LNUM  6
#define FDIM  2688
#define VDIM  50304
#define NCH   16     // wkv chunks
#define LCH   64     // chunk length

#define WSZ   (CDIM * CDIM)              // 589824
#define WIN_OFF  (6 * WSZ)               // 3538944
#define WOUT_OFF (WIN_OFF + CDIM * FDIM) // 5603328
#define WBUF_ELEMS (WOUT_OFF + FDIM * CDIM)  // 7667712 elems per layer

typedef __attribute__((ext_vector_type(4))) float f32x4;
typedef __attribute__((ext_vector_type(8))) short s16x8;

__device__ __forceinline__ ushort f2bf(float f) {
    union { float fv; unsigned u; } v; v.fv = f;
    unsigned r = v.u + 0x7fffu + ((v.u >> 16) & 1u);   // RNE
    return (ushort)(r >> 16);
}

__device__ __forceinline__ void gload_lds16(const ushort* g, ushort* l) {
    __builtin_amdgcn_global_load_lds(
        (const __attribute__((address_space(1))) void*)g,
        (__attribute__((address_space(3))) void*)l, 16, 0, 0);
}

template <int N_>
__device__ __forceinline__ void wait_vm() {
    if constexpr (N_ == 0)      asm volatile("s_waitcnt vmcnt(0)" ::: "memory");
    else if constexpr (N_ == 4) asm volatile("s_waitcnt vmcnt(4)" ::: "memory");
    else if constexpr (N_ == 6) asm volatile("s_waitcnt vmcnt(6)" ::: "memory");
    else if constexpr (N_ == 8) asm volatile("s_waitcnt vmcnt(8)" ::: "memory");
    else                        asm volatile("s_waitcnt vmcnt(12)" ::: "memory");
}
__device__ __forceinline__ void barrier_asm() {
    asm volatile("s_barrier" ::: "memory");
}

// ---------------- transpose + f32->bf16 convert: out[n][k] = bf16(in[k][n]) --
__device__ __forceinline__ void trans_tile(const float* __restrict__ in,
        ushort* __restrict__ out, int R, int C, int tk, int tn) {
    __shared__ float tile[64][65];
    int tid = threadIdx.x;
    int r = tid >> 4, c4 = (tid & 15) << 2;
    int k0 = tk << 6, n0 = tn << 6;
    #pragma unroll
    for (int j = 0; j < 4; j++) {
        int rr = r + j * 16;
        float4 f = *(const float4*)&in[(size_t)(k0 + rr) * C + n0 + c4];
        tile[rr][c4 + 0] = f.x; tile[rr][c4 + 1] = f.y;
        tile[rr][c4 + 2] = f.z; tile[rr][c4 + 3] = f.w;
    }
    __syncthreads();
    #pragma unroll
    for (int j = 0; j < 4; j++) {
        int n = r + j * 16;
        ushort4 u;
        u.x = f2bf(tile[c4 + 0][n]);
        u.y = f2bf(tile[c4 + 1][n]);
        u.z = f2bf(tile[c4 + 2][n]);
        u.w = f2bf(tile[c4 + 3][n]);
        *(ushort4*)&out[(size_t)(n0 + n) * R + k0 + c4] = u;
    }
}

__global__ __launch_bounds__(256)
void k_trans(const float* __restrict__ in, ushort* __restrict__ out, int R, int C) {
    trans_tile(in, out, R, C, blockIdx.y, blockIdx.x);
}

// per-layer tile mapping (1872 tiles)
__device__ __forceinline__ void conv_layer_tile(int t,
        const float* p0, const float* p1, const float* p2, const float* p3,
        const float* p4, const float* p5, const float* pWin, const float* pWout,
        ushort* wl) {
    const float* in; ushort* out; int R, C, tk, tn;
    if (t < 864) {
        int mi = t / 144, tt = t % 144;
        switch (mi) {
            case 0: in = p0; break; case 1: in = p1; break;
            case 2: in = p2; break; case 3: in = p3; break;
            case 4: in = p4; break; default: in = p5; break;
        }
        out = wl + (size_t)mi * WSZ; R = 768; C = 768;
        tk = tt / 12; tn = tt % 12;
    } else if (t < 1368) {
        int tt = t - 864;
        in = pWin; out = wl + WIN_OFF; R = 768; C = 2688;
        tk = tt / 42; tn = tt % 42;
    } else {
        int tt = t - 1368;
        in = pWout; out = wl + WOUT_OFF; R = 2688; C = 768;
        tk = tt / 12; tn = tt % 12;
    }
    trans_tile(in, out, R, C, tk, tn);
}

__global__ __launch_bounds__(256)
void k_conv_layer(const float* p0, const float* p1, const float* p2,
                  const float* p3, const float* p4, const float* p5,
                  const float* pWin, const float* pWout, ushort* wl) {
    conv_layer_tile(blockIdx.x, p0, p1, p2, p3, p4, p5, pWin, pWout, wl);
}

// all 6 layers + unembed in one launch (6*1872 + 9432 = 20664 blocks)
__global__ __launch_bounds__(256)
void k_conv_all(const float* Wr, const float* Wk, const float* Wv,
                const float* Wg, const float* Wo, const float* Wcg,
                const float* Win, const float* Wout, const float* unemb,
                ushort* wbuf, ushort* ubuf) {
    int b = blockIdx.x;
    if (b < 6 * 1872) {
        int l = b / 1872, t = b % 1872;
        conv_layer_tile(t,
            Wr + (size_t)l * WSZ, Wk + (size_t)l * WSZ, Wv + (size_t)l * WSZ,
            Wg + (size_t)l * WSZ, Wo + (size_t)l * WSZ, Wcg + (size_t)l * WSZ,
            Win + (size_t)l * CDIM * FDIM, Wout + (size_t)l * FDIM * CDIM,
            wbuf + (size_t)l * WBUF_ELEMS);
    } else {
        int t = b - 6 * 1872;              // 0..9431
        int tk = t / 786, tn = t % 786;    // R=768, C=VDIM
        trans_tile(unemb, ubuf, CDIM, VDIM, tk, tn);
    }
}

// ---------------- LayerNorm over C=768 -> bf16 (head input) ----------------
__global__ __launch_bounds__(256)
void k_ln_bf(const float* __restrict__ x, const float* __restrict__ wb,
             ushort* __restrict__ out) {
    int t = blockIdx.x, tid = threadIdx.x;
    float v[3]; float s = 0.f, s2 = 0.f;
    #pragma unroll
    for (int j = 0; j < 3; j++) {
        v[j] = x[(size_t)t * CDIM + tid + j * 256];
        s += v[j]; s2 += v[j] * v[j];
    }
    #pragma unroll
    for (int m = 32; m; m >>= 1) { s += __shfl_xor(s, m); s2 += __shfl_xor(s2, m); }
    __shared__ float rs[4], rq[4];
    int w = tid >> 6;
    if ((tid & 63) == 0) { rs[w] = s; rq[w] = s2; }
    __syncthreads();
    s = rs[0] + rs[1] + rs[2] + rs[3];
    s2 = rq[0] + rq[1] + rq[2] + rq[3];
    float mu = s * (1.f / CDIM);
    float inv = rsqrtf(s2 * (1.f / CDIM) - mu * mu + 1e-5f);
    #pragma unroll
    for (int j = 0; j < 3; j++) {
        int c = tid + j * 256;
        out[(size_t)t * CDIM + c] = f2bf((v[j] - mu) * inv * wb[c] + wb[CDIM + c]);
    }
}

// ---------------- embed lookup + LN -> f32 residual stream ----------------
__global__ __launch_bounds__(256)
void k_embed_ln(const int* __restrict__ tok, const float* __restrict__ embed,
                const float* __restrict__ wb, float* __restrict__ xout) {
    int t = blockIdx.x, tid = threadIdx.x;
    const float* row = embed + (size_t)tok[t] * CDIM;
    float v[3]; float s = 0.f, s2 = 0.f;
    #pragma unroll
    for (int j = 0; j < 3; j++) {
        v[j] = row[tid + j * 256]; s += v[j]; s2 += v[j] * v[j];
    }
    #pragma unroll
    for (int m = 32; m; m >>= 1) { s += __shfl_xor(s, m); s2 += __shfl_xor(s2, m); }
    __shared__ float rs[4], rq[4];
    int w = tid >> 6;
    if ((tid & 63) == 0) { rs[w] = s; rq[w] = s2; }
    __syncthreads();
    s = rs[0] + rs[1] + rs[2] + rs[3];
    s2 = rq[0] + rq[1] + rq[2] + rq[3];
    float mu = s * (1.f / CDIM);
    float inv = rsqrtf(s2 * (1.f / CDIM) - mu * mu + 1e-5f);
    #pragma unroll
    for (int j = 0; j < 3; j++) {
        int c = tid + j * 256;
        xout[(size_t)t * CDIM + c] = (v[j] - mu) * inv * wb[c] + wb[CDIM + c];
    }
}

// ---------------- fused LN + token-shift lerp -> NM bf16 mix buffers --------
template <int NM>
__global__ __launch_bounds__(256)
void k_lnlerp(const float* __restrict__ x, const float* __restrict__ lnw,
              const float* __restrict__ ts, ushort* __restrict__ mix) {
    int t = blockIdx.x, tid = threadIdx.x;
    bool has = (t > 0);
    float vb[3], va[3];
    float sb = 0.f, qb = 0.f, sa = 0.f, qa = 0.f;
    #pragma unroll
    for (int j = 0; j < 3; j++) {
        int c = tid + j * 256;
        vb[j] = x[(size_t)t * CDIM + c];
        sb += vb[j]; qb += vb[j] * vb[j];
        va[j] = has ? x[(size_t)(t - 1) * CDIM + c] : 0.f;
        sa += va[j]; qa += va[j] * va[j];
    }
    #pragma unroll
    for (int m = 32; m; m >>= 1) {
        sb += __shfl_xor(sb, m); qb += __shfl_xor(qb, m);
        sa += __shfl_xor(sa, m); qa += __shfl_xor(qa, m);
    }
    __shared__ float r0[4], r1[4], r2[4], r3[4];
    int w = tid >> 6;
    if ((tid & 63) == 0) { r0[w] = sb; r1[w] = qb; r2[w] = sa; r3[w] = qa; }
    __syncthreads();
    sb = r0[0] + r0[1] + r0[2] + r0[3]; qb = r1[0] + r1[1] + r1[2] + r1[3];
    sa = r2[0] + r2[1] + r2[2] + r2[3]; qa = r3[0] + r3[1] + r3[2] + r3[3];
    float mub = sb * (1.f / CDIM);
    float invb = rsqrtf(qb * (1.f / CDIM) - mub * mub + 1e-5f);
    float mua = sa * (1.f / CDIM);
    float inva = rsqrtf(qa * (1.f / CDIM) - mua * mua + 1e-5f);
    #pragma unroll
    for (int j = 0; j < 3; j++) {
        int c = tid + j * 256;
        float wgt = lnw[c], bia = lnw[CDIM + c];
        float xb = (vb[j] - mub) * invb * wgt + bia;
        float xa = has ? (va[j] - mua) * inva * wgt + bia : 0.f;
        #pragma unroll
        for (int m = 0; m < NM; m++) {
            float tv = ts[m * CDIM + c];
            mix[((size_t)m * T_LEN + t) * CDIM + c] = f2bf(xa + (xb - xa) * tv);
        }
    }
}

// ---------------- bf16 MFMA GEMM body: C = A[M][K] @ Bt[N][K]^T -------------
// BK=64, double-buffered LDS, 2-deep pipeline with COUNTED vmcnt (T4):
//   prologue: stage(buf0,t0), stage(buf1,t1)           [2*LD in flight]
//   iter t:   wait vmcnt(LD)  -> tile t's loads done, t+1's still flying
//             s_barrier; compute(cur); s_barrier; stage(cur, t+2)
// Loads get a full iteration of latency cover. Raw asm barriers with
// "memory" clobber pin ds_read/gload ordering (m152/m218 discipline).
// EPI: 0 = f32, 1 = resid+f32, 2 = relu^2 -> bf16, 3 = resid + v*sigmoid(gate)
template <int BM, int BN, int EPI>
__device__ __forceinline__ void gemm_body(
        const ushort* __restrict__ A, const ushort* __restrict__ Bt,
        float* __restrict__ Cf, ushort* __restrict__ Cb,
        const float* __restrict__ resid, const float* __restrict__ gate,
        int N, int K, int mb, int nb, ushort* Al, ushort* Bl) {
    const int tid = threadIdx.x, lane = tid & 63, wave = tid >> 6;
    constexpr int WM = BM / 2, WN = BN / 2, FM = WM / 16, FN = WN / 16;
    const int wm = (wave >> 1) * WM, wn = (wave & 1) * WN;
    constexpr int AR = (BM * 8) / 256;   // 16B slots per thread (BK=64)
    constexpr int BR = (BN * 8) / 256;
    constexpr int LD = AR + BR;          // VMEM ops per stage per thread

    auto stage = [&](int buf, int kt) {
        int k0 = kt << 6;
        #pragma unroll
        for (int r = 0; r < AR; r++) {
            int slot = tid + r * 256;
            int row = slot >> 3, g = slot & 7;
            int gk = ((g ^ (row & 7)) << 3);
            gload_lds16(A + (size_t)(mb + row) * K + k0 + gk,
                        &Al[buf * BM * 64 + slot * 8]);
        }
        #pragma unroll
        for (int r = 0; r < BR; r++) {
            int slot = tid + r * 256;
            int row = slot >> 3, g = slot & 7;
            int gk = ((g ^ (row & 7)) << 3);
            gload_lds16(Bt + (size_t)(nb + row) * K + k0 + gk,
                        &Bl[buf * BN * 64 + slot * 8]);
        }
    };

    f32x4 acc[FM][FN];
    #pragma unroll
    for (int i = 0; i < FM; i++)
        #pragma unroll
        for (int j = 0; j < FN; j++) acc[i][j] = (f32x4)0.f;

    const int nt = K >> 6;               // K is always >= 768 here (nt >= 12)
    stage(0, 0);
    stage(1, 1);
    int cur = 0;
    for (int t = 0; t < nt; t++) {
        if (t + 1 < nt) wait_vm<LD>();   // tile t ready; tile t+1 in flight
        else            wait_vm<0>();
        barrier_asm();
        const ushort* Ab = &Al[cur * BM * 64];
        const ushort* Bb = &Bl[cur * BN * 64];
        const int kq = lane >> 4, ln15 = lane & 15;
        #pragma unroll
        for (int s = 0; s < 2; s++) {
            s16x8 af[FM], bfr[FN];
            #pragma unroll
            for (int i = 0; i < FM; i++) {
                int row = wm + i * 16 + ln15;
                int g = (s * 4 + kq) ^ (row & 7);
                af[i] = *(const s16x8*)&Ab[row * 64 + g * 8];
            }
            #pragma unroll
            for (int j = 0; j < FN; j++) {
                int row = wn + j * 16 + ln15;
                int g = (s * 4 + kq) ^ (row & 7);
                bfr[j] = *(const s16x8*)&Bb[row * 64 + g * 8];
            }
            #pragma unroll
            for (int i = 0; i < FM; i++)
                #pragma unroll
                for (int j = 0; j < FN; j++)
                    acc[i][j] = __builtin_amdgcn_mfma_f32_16x16x32_bf16(
                        af[i], bfr[j], acc[i][j], 0, 0, 0);
        }
        barrier_asm();                    // all waves done reading buf cur
        if (t + 2 < nt) stage(cur, t + 2);
        cur ^= 1;
    }
    #pragma unroll
    for (int i = 0; i < FM; i++) {
        int rbase = mb + wm + i * 16 + (lane >> 4) * 4;
        #pragma unroll
        for (int j = 0; j < FN; j++) {
            int col = nb + wn + j * 16 + (lane & 15);
            #pragma unroll
            for (int r = 0; r < 4; r++) {
                size_t idx = (size_t)(rbase + r) * N + col;
                float vv = acc[i][j][r];
                if constexpr (EPI == 0) {
                    Cf[idx] = vv;
                } else if constexpr (EPI == 1) {
                    Cf[idx] = resid[idx] + vv;
                } else if constexpr (EPI == 2) {
                    float z = vv > 0.f ? vv * vv : 0.f;
                    Cb[idx] = f2bf(z);
                } else {
                    float gv = gate[idx];
                    Cf[idx] = resid[idx] + vv / (1.f + __expf(-gv));
                }
            }
        }
    }
}

template <int BM, int BN, int EPI, bool BATCH>
__global__ __launch_bounds__(256)
void k_gemm_std(const ushort* __restrict__ A, const ushort* __restrict__ Bt,
                float* __restrict__ Cf, ushort* __restrict__ Cb,
                const float* __restrict__ resid, const float* __restrict__ gate,
                int N, int K) {
    __shared__ __align__(16) ushort Al[2 * BM * 64];
    __shared__ __align__(16) ushort Bl[2 * BN * 64];
    if constexpr (BATCH) {
        int z = blockIdx.z;
        A  += (size_t)z * T_LEN * CDIM;
        Bt += (size_t)z * CDIM * CDIM;
        Cf += (size_t)z * T_LEN * CDIM;
    }
    gemm_body<BM, BN, EPI>(A, Bt, Cf, Cb, resid, gate, N, K,
                           blockIdx.y * BM, blockIdx.x * BN, Al, Bl);
}

// head GEMM: XCD-aware mapping so the 8 mb-blocks of one nb-panel share an XCD L2
__global__ __launch_bounds__(256)
void k_gemm_head(const ushort* __restrict__ A, const ushort* __restrict__ Bt,
                 float* __restrict__ C) {
    __shared__ __align__(16) ushort Al[2 * 128 * 64];
    __shared__ __align__(16) ushort Bl[2 * 128 * 64];
    int id = blockIdx.x;
    int xcd = id & 7, slot = id >> 3;
    int mb = slot & 7, nbl = slot >> 3;
    int nb = nbl * 8 + xcd;                  // bijective, balanced
    if (nb >= VDIM / 128) return;
    gemm_body<128, 128, 0>(A, Bt, C, nullptr, nullptr, nullptr,
                           VDIM, CDIM, mb * 128, nb * 128, Al, Bl);
}

// channel-mixer Win (relu^2 -> hb) + Wcg (f32 gcm) merged, 128x64 tiles
__global__ __launch_bounds__(256)
void k_cmix(const ushort* __restrict__ mix, const ushort* __restrict__ wl,
            ushort* __restrict__ hb, float* __restrict__ gcm) {
    __shared__ __align__(16) ushort Al[2 * 128 * 64];
    __shared__ __align__(16) ushort Bl[2 * 64 * 64];
    int bx = blockIdx.x, mb = blockIdx.y * 128;
    if (bx < FDIM / 64) {
        gemm_body<128, 64, 2>(mix, wl + WIN_OFF, nullptr, hb, nullptr, nullptr,
                              FDIM, CDIM, mb, bx * 64, Al, Bl);
    } else {
        gemm_body<128, 64, 0>(mix + (size_t)T_LEN * CDIM, wl + 5 * WSZ, gcm,
                              nullptr, nullptr, nullptr, CDIM, CDIM, mb,
                              (bx - FDIM / 64) * 64, Al, Bl);
    }
}

// ---------------- WKV chunked scan ----------------
// pass1: per-chunk local state  Stil[c][h][k][v] = sum_j w^(63-j) k_j[k] v_j[v]
__global__ __launch_bounds__(256)
void k_wkv1(const float* __restrict__ kb, const float* __restrict__ vb,
            const float* __restrict__ decay, float* __restrict__ Stil) {
    int c = blockIdx.x / HNUM, h = blockIdx.x % HNUM;
    __shared__ float kl[4096], vl[4096], wsh[64];
    int tid = threadIdx.x;
    for (int idx = tid; idx < 4096; idx += 256) {
        int j = idx >> 6, cc = idx & 63;
        size_t g = (size_t)(c * LCH + j) * CDIM + h * 64 + cc;
        kl[idx] = kb[g]; vl[idx] = vb[g];
    }
    if (tid < 64) wsh[tid] = expf(-expf(decay[h * 64 + tid]));
    __syncthreads();
    int k = tid >> 2, v0 = (tid & 3) * 16;
    float w = wsh[k], f = 1.f;
    float s[16];
    #pragma unroll
    for (int i = 0; i < 16; i++) s[i] = 0.f;
    for (int j = 63; j >= 0; --j) {
        float kw = kl[j * 64 + k] * f;
        #pragma unroll
        for (int i = 0; i < 16; i++) s[i] += kw * vl[j * 64 + v0 + i];
        f *= w;
    }
    float* dst = Stil + ((size_t)(c * HNUM + h) << 12) + k * 64 + v0;
    #pragma unroll
    for (int i = 0; i < 16; i++) dst[i] = s[i];
}

// pass2+3 merged: each (c,h) block computes its own chunk-prefix from Stil,
// then replays the chunk; fused GroupNorm*silu(gate) epilogue -> bf16 y.
__global__ __launch_bounds__(256)
void k_wkv23(const float* __restrict__ rb, const float* __restrict__ kb,
             const float* __restrict__ vb, const float* __restrict__ Stil,
             const float* __restrict__ decay, const float* __restrict__ bonus,
             const float* __restrict__ gate, const float* __restrict__ gnw,
             ushort* __restrict__ y) {
    int c = blockIdx.x / HNUM, h = blockIdx.x % HNUM;
    __shared__ float rl[4096], kl[4096], vl[4096];
    __shared__ float part[4][4096];
    __shared__ float wsh[64], bsh[64];
    int tid = threadIdx.x;
    for (int idx = tid; idx < 4096; idx += 256) {
        int j = idx >> 6, cc = idx & 63;
        size_t g = (size_t)(c * LCH + j) * CDIM + h * 64 + cc;
        rl[idx] = rb[g]; kl[idx] = kb[g]; vl[idx] = vb[g];
    }
    if (tid < 64) {
        wsh[tid] = expf(-expf(decay[h * 64 + tid]));
        bsh[tid] = bonus[h * 64 + tid];
    }
    __syncthreads();
    int v = tid & 63, kg = tid >> 6;
    float S[16], wr[16], br[16], w64[16];
    #pragma unroll
    for (int i = 0; i < 16; i++) {
        S[i] = 0.f;
        wr[i] = wsh[kg * 16 + i];
        br[i] = bsh[kg * 16 + i];
        float e = expf(decay[h * 64 + kg * 16 + i]);
        w64[i] = expf(-64.f * e);                    // w^64
    }
    for (int cc = 0; cc < c; cc++) {                 // chunk-prefix stitch
        const float* sp = Stil + ((size_t)(cc * HNUM + h) << 12);
        #pragma unroll
        for (int i = 0; i < 16; i++)
            S[i] = S[i] * w64[i] + sp[(kg * 16 + i) * 64 + v];
    }
    for (int j = 0; j < 64; j++) {
        float vj = vl[j * 64 + v];
        const float4* kp = (const float4*)&kl[j * 64 + kg * 16];
        const float4* rp = (const float4*)&rl[j * 64 + kg * 16];
        float rsum = 0.f;
        #pragma unroll
        for (int q = 0; q < 4; q++) {
            float4 k4 = kp[q], r4 = rp[q];
            const float* kf = (const float*)&k4;
            const float* rf = (const float*)&r4;
            #pragma unroll
            for (int e = 0; e < 4; e++) {
                int i = q * 4 + e;
                float a = kf[e] * vj;
                rsum += rf[e] * (S[i] + a * br[i]);
                S[i] = S[i] * wr[i] + a;
            }
        }
        part[kg][j * 64 + v] = rsum;
    }
    __syncthreads();
    // epilogue: wave kg handles j = kg*16+jj; GroupNorm over 64 lanes + gate
    for (int jj = 0; jj < 16; jj++) {
        int j = kg * 16 + jj;
        float o = part[0][j * 64 + v] + part[1][j * 64 + v] +
                  part[2][j * 64 + v] + part[3][j * 64 + v];
        float s = o, s2 = o * o;
        #pragma unroll
        for (int m = 32; m; m >>= 1) { s += __shfl_xor(s, m); s2 += __shfl_xor(s2, m); }
        float mu = s * (1.f / 64.f);
        float var = s2 * (1.f / 64.f) - mu * mu;
        float xg = (o - mu) * rsqrtf(var + 6.4e-4f);
        int t = c * LCH + j, col = h * 64 + v;
        float gv = gate[(size_t)t * CDIM + col];
        float silu = gv / (1.f + __expf(-gv));
        y[(size_t)t * CDIM + col] = f2bf((xg * gnw[col] + gnw[CDIM + col]) * silu);
    }
}

// ---------------- host ----------------
extern "C" void kernel_launch(void* const* d_in, const int* in_sizes, int n_in,
                              void* d_out, int out_size, void* d_ws, size_t ws_size,
                              hipStream_t stream) {
    const int*   tok      = (const int*)d_in[0];
    const float* embed    = (const float*)d_in[1];
    const float* embed_ln = (const float*)d_in[2];
    const float* tm_ln    = (const float*)d_in[3];
    const float* tm_ts    = (const float*)d_in[4];
    const float* tm_Wr    = (const float*)d_in[5];
    const float* tm_Wk    = (const float*)d_in[6];
    const float* tm_Wv    = (const float*)d_in[7];
    const float* tm_Wg    = (const float*)d_in[8];
    const float* tm_Wo    = (const float*)d_in[9];
    const float* tm_bonus = (const float*)d_in[10];
    const float* tm_decay = (const float*)d_in[11];
    const float* tm_gn    = (const float*)d_in[12];
    const float* cm_ln    = (const float*)d_in[13];
    const float* cm_ts    = (const float*)d_in[14];
    const float* cm_Win   = (const float*)d_in[15];
    const float* cm_Wout  = (const float*)d_in[16];
    const float* cm_Wg    = (const float*)d_in[17];
    const float* head_ln  = (const float*)d_in[18];
    const float* unembed  = (const float*)d_in[19];
    float* out = (float*)d_out;

    const size_t TC = (size_t)T_LEN * CDIM;
    char* wp = (char*)d_ws;
    auto alloc = [&](size_t bytes) {
        char* p = wp; wp += (bytes + 255) & ~(size_t)255; return p;
    };
    float*  x    = (float*)alloc(TC * 4);
    ushort* mix  = (ushort*)alloc(4 * TC * 2);
    float*  rkvg = (float*)alloc(4 * TC * 4);
    float*  gcm  = (float*)alloc(TC * 4);
    ushort* y    = (ushort*)alloc(TC * 2);
    ushort* hb   = (ushort*)alloc((size_t)T_LEN * FDIM * 2);
    float*  Stil = (float*)alloc((size_t)NCH * HNUM * 4096 * 4);
    ushort* ubuf = (ushort*)alloc((size_t)CDIM * VDIM * 2);
    size_t fixed_bytes = (size_t)(wp - (char*)d_ws);
    const size_t per_layer = ((size_t)WBUF_ELEMS * 2 + 255) & ~(size_t)255;
    bool all6 = (fixed_bytes + 6 * per_layer) <= ws_size;
    ushort* wbuf = (ushort*)alloc(all6 ? 6 * per_layer : per_layer);
    if ((size_t)(wp - (char*)d_ws) > ws_size) return;   // fail loudly, no UB

    if (all6) {
        k_conv_all<<<6 * 1872 + 9432, 256, 0, stream>>>(
            tm_Wr, tm_Wk, tm_Wv, tm_Wg, tm_Wo, cm_Wg, cm_Win, cm_Wout,
            unembed, wbuf, ubuf);
    } else {
        k_trans<<<dim3(VDIM / 64, CDIM / 64), 256, 0, stream>>>(
            unembed, ubuf, CDIM, VDIM);
    }
    k_embed_ln<<<T_LEN, 256, 0, stream>>>(tok, embed, embed_ln, x);

    dim3 g64(CDIM / 64, T_LEN / 64);        // (12,16)
    dim3 gQKVG(CDIM / 64, T_LEN / 128, 4);  // (12,8,4) 128x64 tiles
    dim3 gCmix(FDIM / 64 + CDIM / 64, T_LEN / 128);  // (54,8) 128x64 tiles

    for (int l = 0; l < LNUM; l++) {
        ushort* wl = all6 ? (ushort*)((char*)wbuf + (size_t)l * per_layer) : wbuf;
        if (!all6) {
            const size_t lo = (size_t)l * CDIM * CDIM;
            k_conv_layer<<<1872, 256, 0, stream>>>(
                tm_Wr + lo, tm_Wk + lo, tm_Wv + lo, tm_Wg + lo, tm_Wo + lo,
                cm_Wg + lo, cm_Win + (size_t)l * CDIM * FDIM,
                cm_Wout + (size_t)l * FDIM * CDIM, wl);
        }
        const float* dec = tm_decay + (size_t)l * HNUM * KDIM;
        const float* bon = tm_bonus + (size_t)l * HNUM * KDIM;

        // ---- time mixer ----
        k_lnlerp<4><<<T_LEN, 256, 0, stream>>>(x, tm_ln + (size_t)l * 2 * CDIM,
                                               tm_ts + (size_t)l * 4 * CDIM, mix);
        k_gemm_std<128,64,0,true><<<gQKVG, 256, 0, stream>>>(
            mix, wl, rkvg, nullptr, nullptr, nullptr, CDIM, CDIM);
        k_wkv1<<<NCH * HNUM, 256, 0, stream>>>(rkvg + TC, rkvg + 2 * TC, dec, Stil);
        k_wkv23<<<NCH * HNUM, 256, 0, stream>>>(rkvg, rkvg + TC, rkvg + 2 * TC,
            Stil, dec, bon, rkvg + 3 * TC, tm_gn + (size_t)l * 2 * CDIM, y);
        k_gemm_std<64,64,1,false><<<g64, 256, 0, stream>>>(
            y, wl + 4 * WSZ, x, nullptr, x, nullptr, CDIM, CDIM);

        // ---- channel mixer ----
        k_lnlerp<2><<<T_LEN, 256, 0, stream>>>(x, cm_ln + (size_t)l * 2 * CDIM,
                                               cm_ts + (size_t)l * 2 * CDIM, mix);
        k_cmix<<<gCmix, 256, 0, stream>>>(mix, wl, hb, gcm);
        k_gemm_std<64,64,3,false><<<g64, 256, 0, stream>>>(
            hb, wl + WOUT_OFF, x, nullptr, x, gcm, CDIM, FDIM);
    }

    k_ln_bf<<<T_LEN, 256, 0, stream>>>(x, head_ln, mix);
    k_gemm_head<<<3200, 256, 0, stream>>>(mix, ubuf, out);
}

// Round 6
// 954.909 us; speedup vs baseline: 2.1226x; 1.0116x over previous
//
#include <hip/hip_runtime.h>
#include <hip/hip_bf16.h>

#define T_LEN 1024
#define CDIM  768
#define HNUM  12
#define KDIM  64
#define LNUM  6
#define FDIM  2688
#define VDIM  50304
#define NPAD  50432   // 197*256 padded vocab for 256-wide head tiles
#define NCH   16      // wkv chunks
#define LCH   64      // chunk length

#define WSZ   (CDIM * CDIM)              // 589824
#define WIN_OFF  (6 * WSZ)               // 3538944
#define WOUT_OFF (WIN_OFF + CDIM * FDIM) // 5603328
#define WBUF_ELEMS (WOUT_OFF + FDIM * CDIM)  // 7667712 elems per layer

typedef __attribute__((ext_vector_type(4))) float f32x4;
typedef __attribute__((ext_vector_type(8))) short s16x8;

__device__ __forceinline__ ushort f2bf(float f) {
    union { float fv; unsigned u; } v; v.fv = f;
    unsigned r = v.u + 0x7fffu + ((v.u >> 16) & 1u);   // RNE
    return (ushort)(r >> 16);
}

__device__ __forceinline__ void gload_lds16(const ushort* g, ushort* l) {
    __builtin_amdgcn_global_load_lds(
        (const __attribute__((address_space(1))) void*)g,
        (__attribute__((address_space(3))) void*)l, 16, 0, 0);
}

template <int N_>
__device__ __forceinline__ void wait_vm() {
    if constexpr (N_ == 0)      asm volatile("s_waitcnt vmcnt(0)" ::: "memory");
    else if constexpr (N_ == 4) asm volatile("s_waitcnt vmcnt(4)" ::: "memory");
    else if constexpr (N_ == 6) asm volatile("s_waitcnt vmcnt(6)" ::: "memory");
    else if constexpr (N_ == 8) asm volatile("s_waitcnt vmcnt(8)" ::: "memory");
    else                        asm volatile("s_waitcnt vmcnt(12)" ::: "memory");
}
__device__ __forceinline__ void barrier_asm() {
    asm volatile("s_barrier" ::: "memory");
}

// ---------------- transpose + f32->bf16 convert: out[n][k] = bf16(in[k][n]) --
__device__ __forceinline__ void trans_tile(const float* __restrict__ in,
        ushort* __restrict__ out, int R, int C, int tk, int tn) {
    __shared__ float tile[64][65];
    int tid = threadIdx.x;
    int r = tid >> 4, c4 = (tid & 15) << 2;
    int k0 = tk << 6, n0 = tn << 6;
    #pragma unroll
    for (int j = 0; j < 4; j++) {
        int rr = r + j * 16;
        float4 f = *(const float4*)&in[(size_t)(k0 + rr) * C + n0 + c4];
        tile[rr][c4 + 0] = f.x; tile[rr][c4 + 1] = f.y;
        tile[rr][c4 + 2] = f.z; tile[rr][c4 + 3] = f.w;
    }
    __syncthreads();
    #pragma unroll
    for (int j = 0; j < 4; j++) {
        int n = r + j * 16;
        ushort4 u;
        u.x = f2bf(tile[c4 + 0][n]);
        u.y = f2bf(tile[c4 + 1][n]);
        u.z = f2bf(tile[c4 + 2][n]);
        u.w = f2bf(tile[c4 + 3][n]);
        *(ushort4*)&out[(size_t)(n0 + n) * R + k0 + c4] = u;
    }
}

__global__ __launch_bounds__(256)
void k_trans(const float* __restrict__ in, ushort* __restrict__ out, int R, int C) {
    trans_tile(in, out, R, C, blockIdx.y, blockIdx.x);
}

__global__ __launch_bounds__(256)
void k_padzero(ushort* __restrict__ ubuf) {
    size_t base = (size_t)VDIM * CDIM;
    for (int i = threadIdx.x + blockIdx.x * 256; i < (NPAD - VDIM) * CDIM;
         i += 256 * gridDim.x)
        ubuf[base + i] = 0;
}

// per-layer tile mapping (1872 tiles)
__device__ __forceinline__ void conv_layer_tile(int t,
        const float* p0, const float* p1, const float* p2, const float* p3,
        const float* p4, const float* p5, const float* pWin, const float* pWout,
        ushort* wl) {
    const float* in; ushort* out; int R, C, tk, tn;
    if (t < 864) {
        int mi = t / 144, tt = t % 144;
        switch (mi) {
            case 0: in = p0; break; case 1: in = p1; break;
            case 2: in = p2; break; case 3: in = p3; break;
            case 4: in = p4; break; default: in = p5; break;
        }
        out = wl + (size_t)mi * WSZ; R = 768; C = 768;
        tk = tt / 12; tn = tt % 12;
    } else if (t < 1368) {
        int tt = t - 864;
        in = pWin; out = wl + WIN_OFF; R = 768; C = 2688;
        tk = tt / 42; tn = tt % 42;
    } else {
        int tt = t - 1368;
        in = pWout; out = wl + WOUT_OFF; R = 2688; C = 768;
        tk = tt / 12; tn = tt % 12;
    }
    trans_tile(in, out, R, C, tk, tn);
}

__global__ __launch_bounds__(256)
void k_conv_layer(const float* p0, const float* p1, const float* p2,
                  const float* p3, const float* p4, const float* p5,
                  const float* pWin, const float* pWout, ushort* wl) {
    conv_layer_tile(blockIdx.x, p0, p1, p2, p3, p4, p5, pWin, pWout, wl);
}

// all 6 layers + unembed + pad-zero in one launch (6*1872 + 9432 + 1 blocks)
__global__ __launch_bounds__(256)
void k_conv_all(const float* Wr, const float* Wk, const float* Wv,
                const float* Wg, const float* Wo, const float* Wcg,
                const float* Win, const float* Wout, const float* unemb,
                ushort* wbuf, ushort* ubuf) {
    int b = blockIdx.x;
    if (b < 6 * 1872) {
        int l = b / 1872, t = b % 1872;
        conv_layer_tile(t,
            Wr + (size_t)l * WSZ, Wk + (size_t)l * WSZ, Wv + (size_t)l * WSZ,
            Wg + (size_t)l * WSZ, Wo + (size_t)l * WSZ, Wcg + (size_t)l * WSZ,
            Win + (size_t)l * CDIM * FDIM, Wout + (size_t)l * FDIM * CDIM,
            wbuf + (size_t)l * WBUF_ELEMS);
    } else {
        int t = b - 6 * 1872;              // 0..9432
        if (t < 9432) {
            int tk = t / 786, tn = t % 786;    // R=768, C=VDIM (786*64 == VDIM)
            trans_tile(unemb, ubuf, CDIM, VDIM, tk, tn);
        } else {
            size_t base = (size_t)VDIM * CDIM;
            for (int i = threadIdx.x; i < (NPAD - VDIM) * CDIM; i += 256)
                ubuf[base + i] = 0;
        }
    }
}

// ---------------- LayerNorm over C=768 -> bf16 (head input) ----------------
__global__ __launch_bounds__(256)
void k_ln_bf(const float* __restrict__ x, const float* __restrict__ wb,
             ushort* __restrict__ out) {
    int t = blockIdx.x, tid = threadIdx.x;
    float v[3]; float s = 0.f, s2 = 0.f;
    #pragma unroll
    for (int j = 0; j < 3; j++) {
        v[j] = x[(size_t)t * CDIM + tid + j * 256];
        s += v[j]; s2 += v[j] * v[j];
    }
    #pragma unroll
    for (int m = 32; m; m >>= 1) { s += __shfl_xor(s, m); s2 += __shfl_xor(s2, m); }
    __shared__ float rs[4], rq[4];
    int w = tid >> 6;
    if ((tid & 63) == 0) { rs[w] = s; rq[w] = s2; }
    __syncthreads();
    s = rs[0] + rs[1] + rs[2] + rs[3];
    s2 = rq[0] + rq[1] + rq[2] + rq[3];
    float mu = s * (1.f / CDIM);
    float inv = rsqrtf(s2 * (1.f / CDIM) - mu * mu + 1e-5f);
    #pragma unroll
    for (int j = 0; j < 3; j++) {
        int c = tid + j * 256;
        out[(size_t)t * CDIM + c] = f2bf((v[j] - mu) * inv * wb[c] + wb[CDIM + c]);
    }
}

// ---------------- embed lookup + LN -> f32 residual stream ----------------
__global__ __launch_bounds__(256)
void k_embed_ln(const int* __restrict__ tok, const float* __restrict__ embed,
                const float* __restrict__ wb, float* __restrict__ xout) {
    int t = blockIdx.x, tid = threadIdx.x;
    const float* row = embed + (size_t)tok[t] * CDIM;
    float v[3]; float s = 0.f, s2 = 0.f;
    #pragma unroll
    for (int j = 0; j < 3; j++) {
        v[j] = row[tid + j * 256]; s += v[j]; s2 += v[j] * v[j];
    }
    #pragma unroll
    for (int m = 32; m; m >>= 1) { s += __shfl_xor(s, m); s2 += __shfl_xor(s2, m); }
    __shared__ float rs[4], rq[4];
    int w = tid >> 6;
    if ((tid & 63) == 0) { rs[w] = s; rq[w] = s2; }
    __syncthreads();
    s = rs[0] + rs[1] + rs[2] + rs[3];
    s2 = rq[0] + rq[1] + rq[2] + rq[3];
    float mu = s * (1.f / CDIM);
    float inv = rsqrtf(s2 * (1.f / CDIM) - mu * mu + 1e-5f);
    #pragma unroll
    for (int j = 0; j < 3; j++) {
        int c = tid + j * 256;
        xout[(size_t)t * CDIM + c] = (v[j] - mu) * inv * wb[c] + wb[CDIM + c];
    }
}

// ---------------- fused LN + token-shift lerp -> NM bf16 mix buffers --------
template <int NM>
__global__ __launch_bounds__(256)
void k_lnlerp(const float* __restrict__ x, const float* __restrict__ lnw,
              const float* __restrict__ ts, ushort* __restrict__ mix) {
    int t = blockIdx.x, tid = threadIdx.x;
    bool has = (t > 0);
    float vb[3], va[3];
    float sb = 0.f, qb = 0.f, sa = 0.f, qa = 0.f;
    #pragma unroll
    for (int j = 0; j < 3; j++) {
        int c = tid + j * 256;
        vb[j] = x[(size_t)t * CDIM + c];
        sb += vb[j]; qb += vb[j] * vb[j];
        va[j] = has ? x[(size_t)(t - 1) * CDIM + c] : 0.f;
        sa += va[j]; qa += va[j] * va[j];
    }
    #pragma unroll
    for (int m = 32; m; m >>= 1) {
        sb += __shfl_xor(sb, m); qb += __shfl_xor(qb, m);
        sa += __shfl_xor(sa, m); qa += __shfl_xor(qa, m);
    }
    __shared__ float r0[4], r1[4], r2[4], r3[4];
    int w = tid >> 6;
    if ((tid & 63) == 0) { r0[w] = sb; r1[w] = qb; r2[w] = sa; r3[w] = qa; }
    __syncthreads();
    sb = r0[0] + r0[1] + r0[2] + r0[3]; qb = r1[0] + r1[1] + r1[2] + r1[3];
    sa = r2[0] + r2[1] + r2[2] + r2[3]; qa = r3[0] + r3[1] + r3[2] + r3[3];
    float mub = sb * (1.f / CDIM);
    float invb = rsqrtf(qb * (1.f / CDIM) - mub * mub + 1e-5f);
    float mua = sa * (1.f / CDIM);
    float inva = rsqrtf(qa * (1.f / CDIM) - mua * mua + 1e-5f);
    #pragma unroll
    for (int j = 0; j < 3; j++) {
        int c = tid + j * 256;
        float wgt = lnw[c], bia = lnw[CDIM + c];
        float xb = (vb[j] - mub) * invb * wgt + bia;
        float xa = has ? (va[j] - mua) * inva * wgt + bia : 0.f;
        #pragma unroll
        for (int m = 0; m < NM; m++) {
            float tv = ts[m * CDIM + c];
            mix[((size_t)m * T_LEN + t) * CDIM + c] = f2bf(xa + (xb - xa) * tv);
        }
    }
}

// ---------------- bf16 MFMA GEMM body (layers): 2-deep counted-vmcnt -------
// EPI: 0 = f32, 1 = resid+f32, 2 = relu^2 -> bf16, 3 = resid + v*sigmoid(gate)
template <int BM, int BN, int EPI>
__device__ __forceinline__ void gemm_body(
        const ushort* __restrict__ A, const ushort* __restrict__ Bt,
        float* __restrict__ Cf, ushort* __restrict__ Cb,
        const float* __restrict__ resid, const float* __restrict__ gate,
        int N, int K, int mb, int nb, ushort* Al, ushort* Bl) {
    const int tid = threadIdx.x, lane = tid & 63, wave = tid >> 6;
    constexpr int WM = BM / 2, WN = BN / 2, FM = WM / 16, FN = WN / 16;
    const int wm = (wave >> 1) * WM, wn = (wave & 1) * WN;
    constexpr int AR = (BM * 8) / 256;   // 16B slots per thread (BK=64)
    constexpr int BR = (BN * 8) / 256;
    constexpr int LD = AR + BR;          // VMEM ops per stage per thread

    auto stage = [&](int buf, int kt) {
        int k0 = kt << 6;
        #pragma unroll
        for (int r = 0; r < AR; r++) {
            int slot = tid + r * 256;
            int row = slot >> 3, g = slot & 7;
            int gk = ((g ^ (row & 7)) << 3);
            gload_lds16(A + (size_t)(mb + row) * K + k0 + gk,
                        &Al[buf * BM * 64 + slot * 8]);
        }
        #pragma unroll
        for (int r = 0; r < BR; r++) {
            int slot = tid + r * 256;
            int row = slot >> 3, g = slot & 7;
            int gk = ((g ^ (row & 7)) << 3);
            gload_lds16(Bt + (size_t)(nb + row) * K + k0 + gk,
                        &Bl[buf * BN * 64 + slot * 8]);
        }
    };

    f32x4 acc[FM][FN];
    #pragma unroll
    for (int i = 0; i < FM; i++)
        #pragma unroll
        for (int j = 0; j < FN; j++) acc[i][j] = (f32x4)0.f;

    const int nt = K >> 6;
    stage(0, 0);
    stage(1, 1);
    int cur = 0;
    for (int t = 0; t < nt; t++) {
        if (t + 1 < nt) wait_vm<LD>();   // tile t ready; tile t+1 in flight
        else            wait_vm<0>();
        barrier_asm();
        const ushort* Ab = &Al[cur * BM * 64];
        const ushort* Bb = &Bl[cur * BN * 64];
        const int kq = lane >> 4, ln15 = lane & 15;
        #pragma unroll
        for (int s = 0; s < 2; s++) {
            s16x8 af[FM], bfr[FN];
            #pragma unroll
            for (int i = 0; i < FM; i++) {
                int row = wm + i * 16 + ln15;
                int g = (s * 4 + kq) ^ (row & 7);
                af[i] = *(const s16x8*)&Ab[row * 64 + g * 8];
            }
            #pragma unroll
            for (int j = 0; j < FN; j++) {
                int row = wn + j * 16 + ln15;
                int g = (s * 4 + kq) ^ (row & 7);
                bfr[j] = *(const s16x8*)&Bb[row * 64 + g * 8];
            }
            #pragma unroll
            for (int i = 0; i < FM; i++)
                #pragma unroll
                for (int j = 0; j < FN; j++)
                    acc[i][j] = __builtin_amdgcn_mfma_f32_16x16x32_bf16(
                        af[i], bfr[j], acc[i][j], 0, 0, 0);
        }
        barrier_asm();                    // all waves done reading buf cur
        if (t + 2 < nt) stage(cur, t + 2);
        cur ^= 1;
    }
    #pragma unroll
    for (int i = 0; i < FM; i++) {
        int rbase = mb + wm + i * 16 + (lane >> 4) * 4;
        #pragma unroll
        for (int j = 0; j < FN; j++) {
            int col = nb + wn + j * 16 + (lane & 15);
            #pragma unroll
            for (int r = 0; r < 4; r++) {
                size_t idx = (size_t)(rbase + r) * N + col;
                float vv = acc[i][j][r];
                if constexpr (EPI == 0) {
                    Cf[idx] = vv;
                } else if constexpr (EPI == 1) {
                    Cf[idx] = resid[idx] + vv;
                } else if constexpr (EPI == 2) {
                    float z = vv > 0.f ? vv * vv : 0.f;
                    Cb[idx] = f2bf(z);
                } else {
                    float gv = gate[idx];
                    Cf[idx] = resid[idx] + vv / (1.f + __expf(-gv));
                }
            }
        }
    }
}

template <int BM, int BN, int EPI, bool BATCH>
__global__ __launch_bounds__(256)
void k_gemm_std(const ushort* __restrict__ A, const ushort* __restrict__ Bt,
                float* __restrict__ Cf, ushort* __restrict__ Cb,
                const float* __restrict__ resid, const float* __restrict__ gate,
                int N, int K) {
    __shared__ __align__(16) ushort Al[2 * BM * 64];
    __shared__ __align__(16) ushort Bl[2 * BN * 64];
    if constexpr (BATCH) {
        int z = blockIdx.z;
        A  += (size_t)z * T_LEN * CDIM;
        Bt += (size_t)z * CDIM * CDIM;
        Cf += (size_t)z * T_LEN * CDIM;
    }
    gemm_body<BM, BN, EPI>(A, Bt, Cf, Cb, resid, gate, N, K,
                           blockIdx.y * BM, blockIdx.x * BN, Al, Bl);
}

// ---------------- head GEMM: 256x256 tile, 8 waves, phase-split + setprio ---
// 1024 x NPAD(50432) x 768; depth-2 counted vmcnt; 128 KB dynamic LDS.
__global__ __launch_bounds__(512)
void k_head256(const ushort* __restrict__ A, const ushort* __restrict__ Bt,
               float* __restrict__ C) {
    extern __shared__ __align__(16) ushort lds[];
    ushort* Al = lds;                 // [2][256*64]
    ushort* Bl = lds + 2 * 16384;     // [2][256*64]
    const int tid = threadIdx.x, lane = tid & 63, wave = tid >> 6;
    // bijective XCD chunking (m204): the 4 mb-blocks of one nb-panel share an XCD
    const int total = gridDim.x;            // 788
    int q = total >> 3, r = total & 7;
    int xcd = blockIdx.x & 7, loc = blockIdx.x >> 3;
    int work = (xcd < r ? xcd * (q + 1) : r * (q + 1) + (xcd - r) * q) + loc;
    const int nbase = (work >> 2) * 256, mbase = (work & 3) * 256;
    const int wm = (wave >> 2) * 128, wn = (wave & 3) * 64;

    auto stage = [&](int buf, int kt) {
        int k0 = kt << 6;
        #pragma unroll
        for (int rr = 0; rr < 4; rr++) {
            int slot = tid + rr * 512;
            int row = slot >> 3, g = slot & 7;
            int gk = ((g ^ (row & 7)) << 3);
            gload_lds16(A + (size_t)(mbase + row) * CDIM + k0 + gk,
                        &Al[buf * 16384 + slot * 8]);
        }
        #pragma unroll
        for (int rr = 0; rr < 4; rr++) {
            int slot = tid + rr * 512;
            int row = slot >> 3, g = slot & 7;
            int gk = ((g ^ (row & 7)) << 3);
            gload_lds16(Bt + (size_t)(nbase + row) * CDIM + k0 + gk,
                        &Bl[buf * 16384 + slot * 8]);
        }
    };

    f32x4 acc[8][4];
    #pragma unroll
    for (int i = 0; i < 8; i++)
        #pragma unroll
        for (int j = 0; j < 4; j++) acc[i][j] = (f32x4)0.f;

    const int kq = lane >> 4, ln15 = lane & 15;
    stage(0, 0);
    stage(1, 1);
    int cur = 0;
    for (int t = 0; t < 12; t++) {
        if (t < 11) wait_vm<8>();        // tile t ready; tile t+1 in flight
        else        wait_vm<0>();
        barrier_asm();
        const ushort* Ab = &Al[cur * 16384];
        const ushort* Bb = &Bl[cur * 16384];
        #pragma unroll
        for (int ks = 0; ks < 2; ks++) {
            s16x8 bfr[4];
            #pragma unroll
            for (int j = 0; j < 4; j++) {
                int row = wn + j * 16 + ln15;
                int g = (ks * 4 + kq) ^ (row & 7);
                bfr[j] = *(const s16x8*)&Bb[row * 64 + g * 8];
            }
            #pragma unroll
            for (int mh = 0; mh < 2; mh++) {
                s16x8 af[4];
                #pragma unroll
                for (int i = 0; i < 4; i++) {
                    int row = wm + mh * 64 + i * 16 + ln15;
                    int g = (ks * 4 + kq) ^ (row & 7);
                    af[i] = *(const s16x8*)&Ab[row * 64 + g * 8];
                }
                asm volatile("s_waitcnt lgkmcnt(0)" ::: "memory");
                __builtin_amdgcn_sched_barrier(0);
                __builtin_amdgcn_s_setprio(1);
                #pragma unroll
                for (int i = 0; i < 4; i++)
                    #pragma unroll
                    for (int j = 0; j < 4; j++)
                        acc[mh * 4 + i][j] = __builtin_amdgcn_mfma_f32_16x16x32_bf16(
                            af[i], bfr[j], acc[mh * 4 + i][j], 0, 0, 0);
                __builtin_amdgcn_s_setprio(0);
            }
        }
        barrier_asm();
        if (t + 2 < 12) stage(cur, t + 2);
        cur ^= 1;
    }
    #pragma unroll
    for (int a = 0; a < 8; a++) {
        int rbase = mbase + wm + (a >> 2) * 64 + (a & 3) * 16 + (lane >> 4) * 4;
        #pragma unroll
        for (int j = 0; j < 4; j++) {
            int col = nbase + wn + j * 16 + ln15;
            if (col < VDIM) {
                #pragma unroll
                for (int rr = 0; rr < 4; rr++)
                    __builtin_nontemporal_store(acc[a][j][rr],
                        &C[(size_t)(rbase + rr) * VDIM + col]);
            }
        }
    }
}

// channel-mixer Win (relu^2 -> hb) + Wcg (f32 gcm) merged, 128x64 tiles
__global__ __launch_bounds__(256)
void k_cmix(const ushort* __restrict__ mix, const ushort* __restrict__ wl,
            ushort* __restrict__ hb, float* __restrict__ gcm) {
    __shared__ __align__(16) ushort Al[2 * 128 * 64];
    __shared__ __align__(16) ushort Bl[2 * 64 * 64];
    int bx = blockIdx.x, mb = blockIdx.y * 128;
    if (bx < FDIM / 64) {
        gemm_body<128, 64, 2>(mix, wl + WIN_OFF, nullptr, hb, nullptr, nullptr,
                              FDIM, CDIM, mb, bx * 64, Al, Bl);
    } else {
        gemm_body<128, 64, 0>(mix + (size_t)T_LEN * CDIM, wl + 5 * WSZ, gcm,
                              nullptr, nullptr, nullptr, CDIM, CDIM, mb,
                              (bx - FDIM / 64) * 64, Al, Bl);
    }
}

// ---------------- WKV chunked scan ----------------
__global__ __launch_bounds__(256)
void k_wkv1(const float* __restrict__ kb, const float* __restrict__ vb,
            const float* __restrict__ decay, float* __restrict__ Stil) {
    int c = blockIdx.x / HNUM, h = blockIdx.x % HNUM;
    __shared__ float kl[4096], vl[4096], wsh[64];
    int tid = threadIdx.x;
    for (int idx = tid; idx < 4096; idx += 256) {
        int j = idx >> 6, cc = idx & 63;
        size_t g = (size_t)(c * LCH + j) * CDIM + h * 64 + cc;
        kl[idx] = kb[g]; vl[idx] = vb[g];
    }
    if (tid < 64) wsh[tid] = expf(-expf(decay[h * 64 + tid]));
    __syncthreads();
    int k = tid >> 2, v0 = (tid & 3) * 16;
    float w = wsh[k], f = 1.f;
    float s[16];
    #pragma unroll
    for (int i = 0; i < 16; i++) s[i] = 0.f;
    for (int j = 63; j >= 0; --j) {
        float kw = kl[j * 64 + k] * f;
        #pragma unroll
        for (int i = 0; i < 16; i++) s[i] += kw * vl[j * 64 + v0 + i];
        f *= w;
    }
    float* dst = Stil + ((size_t)(c * HNUM + h) << 12) + k * 64 + v0;
    #pragma unroll
    for (int i = 0; i < 16; i++) dst[i] = s[i];
}

// pass2+3 merged + fused GroupNorm*silu(gate) -> bf16 y
__global__ __launch_bounds__(256)
void k_wkv23(const float* __restrict__ rb, const float* __restrict__ kb,
             const float* __restrict__ vb, const float* __restrict__ Stil,
             const float* __restrict__ decay, const float* __restrict__ bonus,
             const float* __restrict__ gate, const float* __restrict__ gnw,
             ushort* __restrict__ y) {
    int c = blockIdx.x / HNUM, h = blockIdx.x % HNUM;
    __shared__ float rl[4096], kl[4096], vl[4096];
    __shared__ float part[4][4096];
    __shared__ float wsh[64], bsh[64];
    int tid = threadIdx.x;
    for (int idx = tid; idx < 4096; idx += 256) {
        int j = idx >> 6, cc = idx & 63;
        size_t g = (size_t)(c * LCH + j) * CDIM + h * 64 + cc;
        rl[idx] = rb[g]; kl[idx] = kb[g]; vl[idx] = vb[g];
    }
    if (tid < 64) {
        wsh[tid] = expf(-expf(decay[h * 64 + tid]));
        bsh[tid] = bonus[h * 64 + tid];
    }
    __syncthreads();
    int v = tid & 63, kg = tid >> 6;
    float S[16], wr[16], br[16], w64[16];
    #pragma unroll
    for (int i = 0; i < 16; i++) {
        S[i] = 0.f;
        wr[i] = wsh[kg * 16 + i];
        br[i] = bsh[kg * 16 + i];
        float e = expf(decay[h * 64 + kg * 16 + i]);
        w64[i] = expf(-64.f * e);                    // w^64
    }
    for (int cc = 0; cc < c; cc++) {                 // chunk-prefix stitch
        const float* sp = Stil + ((size_t)(cc * HNUM + h) << 12);
        #pragma unroll
        for (int i = 0; i < 16; i++)
            S[i] = S[i] * w64[i] + sp[(kg * 16 + i) * 64 + v];
    }
    for (int j = 0; j < 64; j++) {
        float vj = vl[j * 64 + v];
        const float4* kp = (const float4*)&kl[j * 64 + kg * 16];
        const float4* rp = (const float4*)&rl[j * 64 + kg * 16];
        float rsum = 0.f;
        #pragma unroll
        for (int qq = 0; qq < 4; qq++) {
            float4 k4 = kp[qq], r4 = rp[qq];
            const float* kf = (const float*)&k4;
            const float* rf = (const float*)&r4;
            #pragma unroll
            for (int e = 0; e < 4; e++) {
                int i = qq * 4 + e;
                float a = kf[e] * vj;
                rsum += rf[e] * (S[i] + a * br[i]);
                S[i] = S[i] * wr[i] + a;
            }
        }
        part[kg][j * 64 + v] = rsum;
    }
    __syncthreads();
    for (int jj = 0; jj < 16; jj++) {
        int j = kg * 16 + jj;
        float o = part[0][j * 64 + v] + part[1][j * 64 + v] +
                  part[2][j * 64 + v] + part[3][j * 64 + v];
        float s = o, s2 = o * o;
        #pragma unroll
        for (int m = 32; m; m >>= 1) { s += __shfl_xor(s, m); s2 += __shfl_xor(s2, m); }
        float mu = s * (1.f / 64.f);
        float var = s2 * (1.f / 64.f) - mu * mu;
        float xg = (o - mu) * rsqrtf(var + 6.4e-4f);
        int t = c * LCH + j, col = h * 64 + v;
        float gv = gate[(size_t)t * CDIM + col];
        float silu = gv / (1.f + __expf(-gv));
        y[(size_t)t * CDIM + col] = f2bf((xg * gnw[col] + gnw[CDIM + col]) * silu);
    }
}

// ---------------- host ----------------
extern "C" void kernel_launch(void* const* d_in, const int* in_sizes, int n_in,
                              void* d_out, int out_size, void* d_ws, size_t ws_size,
                              hipStream_t stream) {
    const int*   tok      = (const int*)d_in[0];
    const float* embed    = (const float*)d_in[1];
    const float* embed_ln = (const float*)d_in[2];
    const float* tm_ln    = (const float*)d_in[3];
    const float* tm_ts    = (const float*)d_in[4];
    const float* tm_Wr    = (const float*)d_in[5];
    const float* tm_Wk    = (const float*)d_in[6];
    const float* tm_Wv    = (const float*)d_in[7];
    const float* tm_Wg    = (const float*)d_in[8];
    const float* tm_Wo    = (const float*)d_in[9];
    const float* tm_bonus = (const float*)d_in[10];
    const float* tm_decay = (const float*)d_in[11];
    const float* tm_gn    = (const float*)d_in[12];
    const float* cm_ln    = (const float*)d_in[13];
    const float* cm_ts    = (const float*)d_in[14];
    const float* cm_Win   = (const float*)d_in[15];
    const float* cm_Wout  = (const float*)d_in[16];
    const float* cm_Wg    = (const float*)d_in[17];
    const float* head_ln  = (const float*)d_in[18];
    const float* unembed  = (const float*)d_in[19];
    float* out = (float*)d_out;

    const size_t TC = (size_t)T_LEN * CDIM;
    char* wp = (char*)d_ws;
    auto alloc = [&](size_t bytes) {
        char* p = wp; wp += (bytes + 255) & ~(size_t)255; return p;
    };
    float*  x    = (float*)alloc(TC * 4);
    ushort* mix  = (ushort*)alloc(4 * TC * 2);
    float*  rkvg = (float*)alloc(4 * TC * 4);
    float*  gcm  = (float*)alloc(TC * 4);
    ushort* y    = (ushort*)alloc(TC * 2);
    ushort* hb   = (ushort*)alloc((size_t)T_LEN * FDIM * 2);
    float*  Stil = (float*)alloc((size_t)NCH * HNUM * 4096 * 4);
    ushort* ubuf = (ushort*)alloc((size_t)NPAD * CDIM * 2);
    size_t fixed_bytes = (size_t)(wp - (char*)d_ws);
    const size_t per_layer = ((size_t)WBUF_ELEMS * 2 + 255) & ~(size_t)255;
    bool all6 = (fixed_bytes + 6 * per_layer) <= ws_size;
    ushort* wbuf = (ushort*)alloc(all6 ? 6 * per_layer : per_layer);
    if ((size_t)(wp - (char*)d_ws) > ws_size) return;   // fail loudly, no UB

    (void)hipFuncSetAttribute((const void*)k_head256,
            hipFuncAttributeMaxDynamicSharedMemorySize, 131072);

    if (all6) {
        k_conv_all<<<6 * 1872 + 9432 + 1, 256, 0, stream>>>(
            tm_Wr, tm_Wk, tm_Wv, tm_Wg, tm_Wo, cm_Wg, cm_Win, cm_Wout,
            unembed, wbuf, ubuf);
    } else {
        k_trans<<<dim3(VDIM / 64, CDIM / 64), 256, 0, stream>>>(
            unembed, ubuf, CDIM, VDIM);
        k_padzero<<<8, 256, 0, stream>>>(ubuf);
    }
    k_embed_ln<<<T_LEN, 256, 0, stream>>>(tok, embed, embed_ln, x);

    dim3 g64(CDIM / 64, T_LEN / 64);        // (12,16)
    dim3 gQKVG(CDIM / 64, T_LEN / 128, 4);  // (12,8,4) 128x64 tiles
    dim3 gCmix(FDIM / 64 + CDIM / 64, T_LEN / 128);  // (54,8) 128x64 tiles

    for (int l = 0; l < LNUM; l++) {
        ushort* wl = all6 ? (ushort*)((char*)wbuf + (size_t)l * per_layer) : wbuf;
        if (!all6) {
            const size_t lo = (size_t)l * CDIM * CDIM;
            k_conv_layer<<<1872, 256, 0, stream>>>(
                tm_Wr + lo, tm_Wk + lo, tm_Wv + lo, tm_Wg + lo, tm_Wo + lo,
                cm_Wg + lo, cm_Win + (size_t)l * CDIM * FDIM,
                cm_Wout + (size_t)l * FDIM * CDIM, wl);
        }
        const float* dec = tm_decay + (size_t)l * HNUM * KDIM;
        const float* bon = tm_bonus + (size_t)l * HNUM * KDIM;

        // ---- time mixer ----
        k_lnlerp<4><<<T_LEN, 256, 0, stream>>>(x, tm_ln + (size_t)l * 2 * CDIM,
                                               tm_ts + (size_t)l * 4 * CDIM, mix);
        k_gemm_std<128,64,0,true><<<gQKVG, 256, 0, stream>>>(
            mix, wl, rkvg, nullptr, nullptr, nullptr, CDIM, CDIM);
        k_wkv1<<<NCH * HNUM, 256, 0, stream>>>(rkvg + TC, rkvg + 2 * TC, dec, Stil);
        k_wkv23<<<NCH * HNUM, 256, 0, stream>>>(rkvg, rkvg + TC, rkvg + 2 * TC,
            Stil, dec, bon, rkvg + 3 * TC, tm_gn + (size_t)l * 2 * CDIM, y);
        k_gemm_std<64,64,1,false><<<g64, 256, 0, stream>>>(
            y, wl + 4 * WSZ, x, nullptr, x, nullptr, CDIM, CDIM);

        // ---- channel mixer ----
        k_lnlerp<2><<<T_LEN, 256, 0, stream>>>(x, cm_ln + (size_t)l * 2 * CDIM,
                                               cm_ts + (size_t)l * 2 * CDIM, mix);
        k_cmix<<<gCmix, 256, 0, stream>>>(mix, wl, hb, gcm);
        k_gemm_std<64,64,3,false><<<g64, 256, 0, stream>>>(
            hb, wl + WOUT_OFF, x, nullptr, x, gcm, CDIM, FDIM);
    }

    k_ln_bf<<<T_LEN, 256, 0, stream>>>(x, head_ln, mix);
    k_head256<<<788, 512, 131072, stream>>>(mix, ubuf, out);
}